// Round 6
// baseline (277.311 us; speedup 1.0000x reference)
//
#include <hip/hip_runtime.h>
#include <stdint.h>

// ---------------------------------------------------------------------------
// GAT layer, dtype-adaptive (probed: fp32 inputs, int32 edge_index, bf16 out).
//   fused:  h = x@W via split-f16 MFMA (fp32-grade), attn dots in epilogue
//           [blocks SB..SB+Gg)]
//           bucketed scatter: 64-node buckets, PER-WAVE LDS histograms +
//           one device atomic per (block,bucket) run-claim (bcnt line-padded
//           64B/bucket), per-wave cursor sub-runs, KCH=8192 [blocks 0..SB)]
//   bagg:   fused demux+aggregate, one block per bucket. Per node: issue asf
//           gather FIRST, then up to 32 h-row loads (4x8, named regs), THEN
//           compute softmax while h loads are in flight (vmcnt only drains
//           to the asf load), then consume. Latency-chain ~2.5x shorter.
//   legacy (N > 131072): per-edge scatter into cnt/esrc + old k_aggregate.
// ---------------------------------------------------------------------------

#define SLOT 64
#define CNTS 16    // counter stride in ints (legacy path)
#define BCNS 16    // bcnt stride in ints = one 64B line per bucket
#define BCAP 1536  // bucket capacity (entries); avg fill 1024, ~16 sigma slack
#define MAXB 2048  // max buckets (N <= 131072); 4 per-wave hists = 32KB LDS
#define KCH  8192  // edges per scatter chunk

typedef __attribute__((ext_vector_type(8))) _Float16 h8;
typedef __attribute__((ext_vector_type(4))) float    f4x;

__device__ __forceinline__ float b2f(unsigned short u) {
    union { unsigned int i; float f; } v; v.i = ((unsigned int)u) << 16; return v.f;
}
__device__ __forceinline__ unsigned short f2b(float f) {
    union { float f; unsigned int i; } v; v.f = f;
    unsigned int i = v.i;
    unsigned int r = (i + 0x7FFFu + ((i >> 16) & 1u)) >> 16;  // RNE
    return (unsigned short)r;
}
__device__ __forceinline__ unsigned short f2h(float f) {
    union { _Float16 h; unsigned short u; } v; v.h = (_Float16)f; return v.u;
}
__device__ __forceinline__ float h2f(unsigned short u) {
    union { _Float16 h; unsigned short u; } v; v.u = u; return (float)v.h;
}

// --- 0. dtype probes --------------------------------------------------------
__global__ void k_detect(const int* __restrict__ eidx, const unsigned int* __restrict__ xw,
                         int* flags) {
    __shared__ int nz, bf;
    if (threadIdx.x == 0) { nz = 0; bf = 0; }
    __syncthreads();
    int bad = 0;
    for (int i = threadIdx.x; i < 1024; i += 256)
        if (eidx[2 * i + 1] != 0) bad = 1;
    if (bad) atomicOr(&nz, 1);
    int hits = 0;
    for (int i = threadIdx.x; i < 4096; i += 256) {
        unsigned int e = (xw[i] >> 7) & 0xFFu;
        if (e >= 0x60u && e < 0xA0u) ++hits;
    }
    atomicAdd(&bf, hits);
    __syncthreads();
    if (threadIdx.x == 0) {
        flags[0] = (nz == 0) ? 1 : 0;   // 1 => int64 edge_index
        flags[1] = (bf > 3072) ? 1 : 0; // 1 => bf16 float tensors
    }
}

__device__ __forceinline__ int edge_at(const int* idx32, const long long* idx64,
                                       int is64, long long pos) {
    return is64 ? (int)idx64[pos] : idx32[pos];
}

// --- 0b. W^T hi/lo f16 + att/bias fp32 -> ws --------------------------------
__global__ void k_prep(const void* __restrict__ Wv, const void* __restrict__ asv,
                       const void* __restrict__ adv, const void* __restrict__ bv,
                       const int* __restrict__ flags,
                       _Float16* __restrict__ Wth, _Float16* __restrict__ Wtl,
                       float* __restrict__ attf /*256*/, float* __restrict__ biasf /*128*/) {
    int isbf = flags[1];
    int tid = blockIdx.x * 256 + threadIdx.x;
    for (int i = tid; i < 16384; i += gridDim.x * 256) {
        int col = i >> 7, k = i & 127;            // Wt[col][k] = W[k][col]
        float w = isbf ? b2f(((const unsigned short*)Wv)[k * 128 + col])
                       : ((const float*)Wv)[k * 128 + col];
        unsigned short hi = f2h(w);
        unsigned short lo = f2h(w - h2f(hi));
        ((unsigned short*)Wth)[i] = hi;
        ((unsigned short*)Wtl)[i] = lo;
    }
    if (blockIdx.x == 0) {
        for (int i = threadIdx.x; i < 128; i += 256) {
            attf[i]       = isbf ? b2f(((const unsigned short*)asv)[i]) : ((const float*)asv)[i];
            attf[128 + i] = isbf ? b2f(((const unsigned short*)adv)[i]) : ((const float*)adv)[i];
            biasf[i]      = isbf ? b2f(((const unsigned short*)bv)[i]) : ((const float*)bv)[i];
        }
    }
}

// --- 1. fused MFMA GEMM (blocks >= SB) + bucketed scatter (blocks < SB) -----
__global__ __launch_bounds__(256) void k_gemm_scatter(
    const void* __restrict__ xv,
    const _Float16* __restrict__ Wth, const _Float16* __restrict__ Wtl,
    const float* __restrict__ attf, const int* __restrict__ flags,
    unsigned short* __restrict__ hbf, float* __restrict__ asf,
    float* __restrict__ adf, int N,
    const int* __restrict__ idx32, const long long* __restrict__ idx64,
    int* __restrict__ bcnt, unsigned* __restrict__ bdat,
    int* __restrict__ cnt, int* __restrict__ esrc,
    int E, int Gg, int SB) {
    __shared__ unsigned short xsh[64 * 128];   // x hi-plane / scatter hists 0,1
    __shared__ unsigned short xsl[64 * 128];   // x lo-plane / scatter hists 2,3
    int tid = threadIdx.x;
    int bid = blockIdx.x;

    if (bid < SB) {                            // ---- bucketed scatter ----
        int is64 = flags[0];
        int NBK = (N + 63) >> 6;
        long long e0 = (long long)bid * KCH;
        long long e1 = e0 + KCH; if (e1 > E) e1 = E;
        if (e0 >= E) return;

        if (NBK <= MAXB) {
            int wid = tid >> 6;
            int* h0 = (int*)xsh; int* h1 = h0 + MAXB;
            int* h2 = (int*)xsl; int* h3 = h2 + MAXB;
            int* hw = (wid == 0) ? h0 : (wid == 1) ? h1 : (wid == 2) ? h2 : h3;
            for (int i = tid; i < NBK; i += 256) { h0[i] = 0; h1[i] = 0; h2[i] = 0; h3[i] = 0; }
            __syncthreads();
            // pass 1: per-wave chunk histograms (intra-wave RMW only)
            for (long long e = e0 + tid; e < e1; e += 256) {
                int d = is64 ? (int)idx64[(long long)E + e] : idx32[E + e];
                atomicAdd(&hw[d >> 6], 1);
            }
            __syncthreads();
            // claim: ONE device atomic per non-empty bucket (64B-padded line);
            // per-wave sub-runs
            for (int b = tid; b < NBK; b += 256) {
                int c0 = h0[b], c1 = h1[b], c2 = h2[b], c3 = h3[b];
                int t = c0 + c1 + c2 + c3;
                int base = (t > 0) ? atomicAdd(&bcnt[(size_t)b * BCNS], t) : 0;
                h0[b] = base;
                h1[b] = base + c0;
                h2[b] = base + c0 + c1;
                h3[b] = base + c0 + c1 + c2;
            }
            __syncthreads();
            // pass 2: place entries at per-wave LDS cursors
            for (long long e = e0 + tid; e < e1; e += 256) {
                int d, s;
                if (is64) {
                    d = (int)idx64[(long long)E + e]; s = (int)idx64[e];
                } else {
                    d = idx32[E + e]; s = idx32[e];
                }
                int b = d >> 6;
                int p = atomicAdd(&hw[b], 1);
                if (p < BCAP)
                    bdat[(size_t)b * BCAP + p] = (unsigned)s | ((unsigned)(d & 63) << 26);
            }
        } else {
            // legacy per-edge path (host memsets cnt, uses old k_aggregate)
            for (long long e = e0 + tid; e < e1; e += 256) {
                int d = edge_at(idx32, idx64, is64, (long long)E + e);
                int s = edge_at(idx32, idx64, is64, e);
                int p = atomicAdd(&cnt[(size_t)d * CNTS], 1);
                if (p < SLOT) esrc[(size_t)d * SLOT + p] = s;
            }
        }
        return;
    }

    // ---- MFMA GEMM (unchanged) ----
    int rb = bid - SB;
    if (rb >= Gg) return;
    int r0 = rb * 64;
    int isbf = flags[1];
    int w = tid >> 6;            // wave id = head id (owns cols [32w, 32w+32))
    int lane = tid & 63;
    int li = lane & 15;          // fragment row/col index
    int g  = lane >> 4;          // k-group
    int c0 = w * 32;

    h8 Bh[2][4], Bl[2][4];
#pragma unroll
    for (int t = 0; t < 2; ++t)
#pragma unroll
        for (int s = 0; s < 4; ++s) {
            size_t o = (size_t)(c0 + 16 * t + li) * 128 + 32 * s + 8 * g;
            Bh[t][s] = *(const h8*)(Wth + o);
            Bl[t][s] = *(const h8*)(Wtl + o);
        }

#pragma unroll
    for (int it = 0; it < 4; ++it) {
        int idx = it * 2048 + tid * 8;         // 8 elements per thread per iter
        int r = idx >> 7, k = idx & 127;
        int gr = r0 + r; if (gr >= N) gr = N - 1;
        float v[8];
        if (isbf) {
            uint4 raw = *(const uint4*)((const unsigned short*)xv + (size_t)gr * 128 + k);
            v[0] = b2f((unsigned short)(raw.x & 0xFFFFu)); v[1] = b2f((unsigned short)(raw.x >> 16));
            v[2] = b2f((unsigned short)(raw.y & 0xFFFFu)); v[3] = b2f((unsigned short)(raw.y >> 16));
            v[4] = b2f((unsigned short)(raw.z & 0xFFFFu)); v[5] = b2f((unsigned short)(raw.z >> 16));
            v[6] = b2f((unsigned short)(raw.w & 0xFFFFu)); v[7] = b2f((unsigned short)(raw.w >> 16));
        } else {
            const float* xf = (const float*)xv;
            float4 a = *(const float4*)(xf + (size_t)gr * 128 + k);
            float4 b = *(const float4*)(xf + (size_t)gr * 128 + k + 4);
            v[0] = a.x; v[1] = a.y; v[2] = a.z; v[3] = a.w;
            v[4] = b.x; v[5] = b.y; v[6] = b.z; v[7] = b.w;
        }
        uint4 PH, PL;
        unsigned int ph[4], pl[4];
#pragma unroll
        for (int jj = 0; jj < 4; ++jj) {
            unsigned short h0 = f2h(v[2 * jj]), h1 = f2h(v[2 * jj + 1]);
            unsigned short l0 = f2h(v[2 * jj] - h2f(h0));
            unsigned short l1 = f2h(v[2 * jj + 1] - h2f(h1));
            ph[jj] = (unsigned int)h0 | ((unsigned int)h1 << 16);
            pl[jj] = (unsigned int)l0 | ((unsigned int)l1 << 16);
        }
        PH.x = ph[0]; PH.y = ph[1]; PH.z = ph[2]; PH.w = ph[3];
        PL.x = pl[0]; PL.y = pl[1]; PL.z = pl[2]; PL.w = pl[3];
        int off = r * 256 + ((2 * k) ^ ((r & 7) << 4));   // 16B-slot XOR swizzle
        *(uint4*)((char*)xsh + off) = PH;
        *(uint4*)((char*)xsl + off) = PL;
    }
    __syncthreads();

    f4x acc[4][2];
#pragma unroll
    for (int m = 0; m < 4; ++m)
#pragma unroll
        for (int t = 0; t < 2; ++t) acc[m][t] = (f4x){0.f, 0.f, 0.f, 0.f};

#pragma unroll
    for (int s = 0; s < 4; ++s) {
#pragma unroll
        for (int m = 0; m < 4; ++m) {
            int row = 16 * m + li;
            int kb = (32 * s + 8 * g) * 2;
            int off = row * 256 + (kb ^ ((row & 7) << 4));
            h8 ah = *(const h8*)((const char*)xsh + off);
            h8 al = *(const h8*)((const char*)xsl + off);
#pragma unroll
            for (int t = 0; t < 2; ++t) {
                acc[m][t] = __builtin_amdgcn_mfma_f32_16x16x32_f16(ah, Bh[t][s], acc[m][t], 0, 0, 0);
                acc[m][t] = __builtin_amdgcn_mfma_f32_16x16x32_f16(al, Bh[t][s], acc[m][t], 0, 0, 0);
                acc[m][t] = __builtin_amdgcn_mfma_f32_16x16x32_f16(ah, Bl[t][s], acc[m][t], 0, 0, 0);
            }
        }
    }

    // Epilogue 1: attn dots from fp32 acc. C/D: col = li, row = 4*g + reg.
    float at_s0 = attf[c0 + li],       at_s1 = attf[c0 + 16 + li];
    float at_d0 = attf[128 + c0 + li], at_d1 = attf[128 + c0 + 16 + li];
#pragma unroll
    for (int m = 0; m < 4; ++m) {
        float s1v[4], s2v[4];
#pragma unroll
        for (int j = 0; j < 4; ++j) {
            s1v[j] = acc[m][0][j] * at_s0 + acc[m][1][j] * at_s1;
            s2v[j] = acc[m][0][j] * at_d0 + acc[m][1][j] * at_d1;
        }
#pragma unroll
        for (int j = 0; j < 4; ++j) {
#pragma unroll
            for (int msk = 1; msk < 16; msk <<= 1) {
                s1v[j] += __shfl_xor(s1v[j], msk);
                s2v[j] += __shfl_xor(s2v[j], msk);
            }
        }
        if (li == 0) {
#pragma unroll
            for (int j = 0; j < 4; ++j) {
                int gr = r0 + 16 * m + 4 * g + j;
                if (gr < N) {
                    asf[(size_t)gr * 4 + w] = s1v[j];
                    adf[(size_t)gr * 4 + w] = s2v[j];
                }
            }
        }
    }

    // Epilogue 2: h -> bf16 via LDS (reuse hi-plane) for coalesced store.
    __syncthreads();
#pragma unroll
    for (int m = 0; m < 4; ++m)
#pragma unroll
        for (int t = 0; t < 2; ++t)
#pragma unroll
            for (int j = 0; j < 4; ++j)
                xsh[(16 * m + 4 * g + j) * 128 + c0 + 16 * t + li] = f2b(acc[m][t][j]);
    __syncthreads();
#pragma unroll
    for (int it = 0; it < 4; ++it) {
        int u = it * 2048 + tid * 8;
        int r = u >> 7, k = u & 127;
        int gr = r0 + r;
        if (gr < N)
            *(uint4*)(hbf + (size_t)gr * 128 + k) = *(const uint4*)(xsh + u);
    }
}

// --- 2. fused demux + aggregate: one block per 64-node bucket ---------------
// Items per node: 0 = self-loop, k = edge k-1; padded to x8 (q=0 padding).
#define LOADV8(vv, bi)                                                        \
    _Pragma("unroll")                                                         \
    for (int k2 = 0; k2 < 8; ++k2) {                                          \
        int it = (bi) * 8 + k2;                                               \
        int s = (it == 0) ? n : ((it <= deg) ? lslot[dl][it - 1] : n);        \
        vv[k2] = *(const unsigned int*)(hbf + (size_t)s * 128 + 2 * lane);    \
    }
#define CONSQ8(vv, bi)                                                        \
    _Pragma("unroll")                                                         \
    for (int k2 = 0; k2 < 8; ++k2) {                                          \
        float q = psh[((bi) * 8 + k2) * 4 + head];                            \
        a0 += q * b2f((unsigned short)vv[k2]);                                \
        a1 += q * b2f((unsigned short)(vv[k2] >> 16));                        \
    }

__global__ __launch_bounds__(256) void k_bagg(
    const unsigned* __restrict__ bdat, const int* __restrict__ bcnt,
    const unsigned short* __restrict__ hbf,
    const float* __restrict__ asf, const float* __restrict__ adf,
    const int* __restrict__ idx32, const long long* __restrict__ idx64,
    const float* __restrict__ biasf, const int* __restrict__ flags,
    void* __restrict__ outv, int N, int E) {
    __shared__ int   lcnt[64];
    __shared__ int   lslot[64][SLOT];          // 16KB
    __shared__ float p_all[4][SLOT * 4];       // 4KB, per-wave transient
    int b = blockIdx.x, tid = threadIdx.x;
    int wid = tid >> 6, lane = tid & 63, head = lane >> 4;

    if (tid < 64) lcnt[tid] = 0;
    __syncthreads();
    int mm = bcnt[(size_t)b * BCNS];
    int ovf = (mm > BCAP);
    if (mm > BCAP) mm = BCAP;
    for (int i = tid; i < mm; i += 256) {      // demux bucket -> LDS CSR
        unsigned e = bdat[(size_t)b * BCAP + i];
        int dl = (int)(e >> 26);
        int p = atomicAdd(&lcnt[dl], 1);
        if (p < SLOT) lslot[dl][p] = (int)(e & 0x03FFFFFFu);
    }
    __syncthreads();

    float b0 = biasf[2 * lane], b1 = biasf[2 * lane + 1];
    float* psh = p_all[wid];
    int isbf = flags[1];
    int is64 = flags[0];

    for (int u = 0; u < 16; ++u) {             // 16 nodes per wave, no block sync
        int dl = wid * 16 + u;
        int n = (b << 6) + dl;
        if (n >= N) break;                     // wave-uniform
        int deg = lcnt[dl];
        bool fb = ovf || (deg > SLOT - 1);
        float4 adv = *(const float4*)(adf + (size_t)n * 4);
        float a0 = 0.f, a1 = 0.f, invh;

        if (!fb) {
            int tot = deg + 1;
            int nb = (tot + 7) >> 3;           // wave-uniform

            // (1) asf gather first (oldest in vmcnt queue); lane>deg reads
            //     row n (valid) and its products are masked to 0 below.
            int sl = (lane == 0) ? n : ((lane <= deg) ? lslot[dl][lane - 1] : n);
            float4 av = *(const float4*)(asf + (size_t)sl * 4);

            // (2) issue up to 32 h-row loads; addresses depend only on lslot.
            unsigned vv0[8], vv1[8], vv2[8], vv3[8];
            LOADV8(vv0, 0)
            if (nb > 1) LOADV8(vv1, 1)
            if (nb > 2) LOADV8(vv2, 2)
            if (nb > 3) LOADV8(vv3, 3)

            // (3) softmax under the h loads (waits only on av).
            float p0 = 0.f, p1 = 0.f, p2 = 0.f, p3 = 0.f;
            if (lane <= deg) {
                float e0 = av.x + adv.x; e0 = fmaxf(e0, 0.2f * e0); p0 = __expf(e0);
                float e1 = av.y + adv.y; e1 = fmaxf(e1, 0.2f * e1); p1 = __expf(e1);
                float e2 = av.z + adv.z; e2 = fmaxf(e2, 0.2f * e2); p2 = __expf(e2);
                float e3 = av.w + adv.w; e3 = fmaxf(e3, 0.2f * e3); p3 = __expf(e3);
            }
            psh[lane * 4 + 0] = p0; psh[lane * 4 + 1] = p1;   // zeros beyond deg
            psh[lane * 4 + 2] = p2; psh[lane * 4 + 3] = p3;   //  -> padded q = 0
            __builtin_amdgcn_wave_barrier();
            asm volatile("s_waitcnt lgkmcnt(0)" ::: "memory");
            __builtin_amdgcn_wave_barrier();

            float ps0 = p0, ps1 = p1, ps2 = p2, ps3 = p3;
#pragma unroll
            for (int m = 1; m < 64; m <<= 1) { // 64-lane butterfly denom
                ps0 += __shfl_xor(ps0, m);
                ps1 += __shfl_xor(ps1, m);
                ps2 += __shfl_xor(ps2, m);
                ps3 += __shfl_xor(ps3, m);
            }
            float den = head == 0 ? ps0 : head == 1 ? ps1 : head == 2 ? ps2 : ps3;
            invh = 1.0f / (den + 1e-16f);

            // (4) consume; q from LDS (cheap), h already landed.
            CONSQ8(vv0, 0)
            if (nb > 1) CONSQ8(vv1, 1)
            if (nb > 2) CONSQ8(vv2, 2)
            if (nb > 3) CONSQ8(vv3, 3)
            // (5) rare tail (deg > 31): sequential batches.
            for (int bi = 4; bi < nb; ++bi) {
                unsigned vt[8];
                LOADV8(vt, bi)
                CONSQ8(vt, bi)
            }
        } else {
            // parachute: deg >= SLOT or bucket overflow. Exact full rescan.
            float adh = head == 0 ? adv.x : head == 1 ? adv.y : head == 2 ? adv.z : adv.w;
            float den = 0.f;
            {   // self-loop
                float ev = asf[(size_t)n * 4 + head] + adh; ev = fmaxf(ev, 0.2f * ev);
                float p = __expf(ev);
                unsigned int v = *(const unsigned int*)(hbf + (size_t)n * 128 + 2 * lane);
                den += p;
                a0 += p * b2f((unsigned short)v);
                a1 += p * b2f((unsigned short)(v >> 16));
            }
            for (int e = 0; e < E; ++e) {
                int d = edge_at(idx32, idx64, is64, (long long)E + e);
                if (d == n) {
                    int s = edge_at(idx32, idx64, is64, e);
                    float ev = asf[(size_t)s * 4 + head] + adh; ev = fmaxf(ev, 0.2f * ev);
                    float p = __expf(ev);
                    unsigned int v = *(const unsigned int*)(hbf + (size_t)s * 128 + 2 * lane);
                    den += p;
                    a0 += p * b2f((unsigned short)v);
                    a1 += p * b2f((unsigned short)(v >> 16));
                }
            }
            invh = 1.0f / (den + 1e-16f);
        }

        a0 = a0 * invh + b0;
        a1 = a1 * invh + b1;
        if (isbf) {
            unsigned int pk = (unsigned int)f2b(a0) | ((unsigned int)f2b(a1) << 16);
            ((unsigned int*)outv)[(size_t)n * 64 + lane] = pk;
        } else {
            float2 f2; f2.x = a0; f2.y = a1;
            *(float2*)((float*)outv + (size_t)n * 128 + 2 * lane) = f2;
        }
        __builtin_amdgcn_wave_barrier();
    }
}

// --- 2L. legacy aggregate (NBK > MAXB only): one wave per node --------------
__global__ __launch_bounds__(256) void k_aggregate(
    const unsigned short* __restrict__ hbf,
    const float* __restrict__ asf, const float* __restrict__ adf,
    const int* __restrict__ cnt, const int* __restrict__ esrc,
    const int* __restrict__ idx32, const long long* __restrict__ idx64,
    const float* __restrict__ biasf, const int* __restrict__ flags,
    void* __restrict__ outv, int N, int E) {
    __shared__ float p_sh_all[4][SLOT * 4];
    __shared__ int   s_sh_all[4][SLOT];
    int wid = threadIdx.x >> 6;
    int lane = threadIdx.x & 63;
    int n = blockIdx.x * 4 + wid;
    if (n >= N) n = N - 1;                     // tail waves redo a node (benign)
    float* p_sh = p_sh_all[wid];
    int*   s_sh = s_sh_all[wid];
    int head = lane >> 4;

    int deg = cnt[(size_t)n * CNTS];           // edges, excl. self-loop
    float4 adv = *(const float4*)(adf + (size_t)n * 4);
    bool fb = (deg > SLOT - 1);                // total deg+1 must fit in 64

    float p0 = 0.f, p1 = 0.f, p2 = 0.f, p3 = 0.f;
    if (!fb && lane <= deg) {                  // phase 1: one item per lane
        int s = (lane == 0) ? n : esrc[(size_t)n * SLOT + lane - 1];
        float4 av = *(const float4*)(asf + (size_t)s * 4);
        float e0 = av.x + adv.x; e0 = fmaxf(e0, 0.2f * e0); p0 = __expf(e0);
        float e1 = av.y + adv.y; e1 = fmaxf(e1, 0.2f * e1); p1 = __expf(e1);
        float e2 = av.z + adv.z; e2 = fmaxf(e2, 0.2f * e2); p2 = __expf(e2);
        float e3 = av.w + adv.w; e3 = fmaxf(e3, 0.2f * e3); p3 = __expf(e3);
        s_sh[lane] = s;
        p_sh[lane * 4 + 0] = p0; p_sh[lane * 4 + 1] = p1;
        p_sh[lane * 4 + 2] = p2; p_sh[lane * 4 + 3] = p3;
    }
    __syncthreads();

    float b0 = biasf[2 * lane], b1 = biasf[2 * lane + 1];
    float a0 = 0.f, a1 = 0.f, invh;

    if (!fb) {
        float ps0 = p0, ps1 = p1, ps2 = p2, ps3 = p3;
#pragma unroll
        for (int m = 1; m < 64; m <<= 1) {     // 64-lane butterfly
            ps0 += __shfl_xor(ps0, m);
            ps1 += __shfl_xor(ps1, m);
            ps2 += __shfl_xor(ps2, m);
            ps3 += __shfl_xor(ps3, m);
        }
        float den = head == 0 ? ps0 : head == 1 ? ps1 : head == 2 ? ps2 : ps3;
        invh = 1.0f / (den + 1e-16f);

        int tot = deg + 1;
        int i = 0;
        for (; i + 3 < tot; i += 4) {          // 4 row-gathers in flight
            int s0 = s_sh[i], s1 = s_sh[i + 1], s2 = s_sh[i + 2], s3 = s_sh[i + 3];
            float q0 = p_sh[i * 4 + head],       q1 = p_sh[(i + 1) * 4 + head];
            float q2 = p_sh[(i + 2) * 4 + head], q3 = p_sh[(i + 3) * 4 + head];
            unsigned int v0 = *(const unsigned int*)(hbf + (size_t)s0 * 128 + 2 * lane);
            unsigned int v1 = *(const unsigned int*)(hbf + (size_t)s1 * 128 + 2 * lane);
            unsigned int v2 = *(const unsigned int*)(hbf + (size_t)s2 * 128 + 2 * lane);
            unsigned int v3 = *(const unsigned int*)(hbf + (size_t)s3 * 128 + 2 * lane);
            a0 += q0 * b2f((unsigned short)v0) + q1 * b2f((unsigned short)v1)
                + q2 * b2f((unsigned short)v2) + q3 * b2f((unsigned short)v3);
            a1 += q0 * b2f((unsigned short)(v0 >> 16)) + q1 * b2f((unsigned short)(v1 >> 16))
                + q2 * b2f((unsigned short)(v2 >> 16)) + q3 * b2f((unsigned short)(v3 >> 16));
        }
        for (; i < tot; ++i) {
            int s0 = s_sh[i];
            float q0 = p_sh[i * 4 + head];
            unsigned int v0 = *(const unsigned int*)(hbf + (size_t)s0 * 128 + 2 * lane);
            a0 += q0 * b2f((unsigned short)v0);
            a1 += q0 * b2f((unsigned short)(v0 >> 16));
        }
    } else {
        int is64 = flags[0];
        float adh = head == 0 ? adv.x : head == 1 ? adv.y : head == 2 ? adv.z : adv.w;
        float den = 0.f;
        {   // self-loop
            float ev = asf[(size_t)n * 4 + head] + adh; ev = fmaxf(ev, 0.2f * ev);
            float p = __expf(ev);
            unsigned int v = *(const unsigned int*)(hbf + (size_t)n * 128 + 2 * lane);
            den += p;
            a0 += p * b2f((unsigned short)v);
            a1 += p * b2f((unsigned short)(v >> 16));
        }
        for (int e = 0; e < E; ++e) {
            int d = edge_at(idx32, idx64, is64, (long long)E + e);
            if (d == n) {
                int s = edge_at(idx32, idx64, is64, e);
                float ev = asf[(size_t)s * 4 + head] + adh; ev = fmaxf(ev, 0.2f * ev);
                float p = __expf(ev);
                unsigned int v = *(const unsigned int*)(hbf + (size_t)s * 128 + 2 * lane);
                den += p;
                a0 += p * b2f((unsigned short)v);
                a1 += p * b2f((unsigned short)(v >> 16));
            }
        }
        invh = 1.0f / (den + 1e-16f);
    }

    a0 = a0 * invh + b0;
    a1 = a1 * invh + b1;
    if (flags[1]) {
        unsigned int pk = (unsigned int)f2b(a0) | ((unsigned int)f2b(a1) << 16);
        ((unsigned int*)outv)[(size_t)n * 64 + lane] = pk;
    } else {
        float2 f2; f2.x = a0; f2.y = a1;
        *(float2*)((float*)outv + (size_t)n * 128 + 2 * lane) = f2;
    }
}

// ---------------------------------------------------------------------------
extern "C" void kernel_launch(void* const* d_in, const int* in_sizes, int n_in,
                              void* d_out, int out_size, void* d_ws, size_t ws_size,
                              hipStream_t stream) {
    const void*      xv    = d_in[0];
    const int*       idx32 = (const int*)d_in[1];
    const long long* idx64 = (const long long*)d_in[1];

    int N = in_sizes[0] / 128;
    int E = in_sizes[1] / 2;

    char* ws = (char*)d_ws;
    size_t o = 0;
    auto alloc = [&](size_t bytes) {
        size_t r = o; o += (bytes + 255) & ~(size_t)255; return r;
    };
    unsigned short* hbf = (unsigned short*)(ws + alloc((size_t)N * 128 * 2));
    _Float16* Wth = (_Float16*)(ws + alloc(16384 * 2));
    _Float16* Wtl = (_Float16*)(ws + alloc(16384 * 2));
    float* attf  = (float*)(ws + alloc(256 * 4));
    float* biasf = (float*)(ws + alloc(128 * 4));
    float* asf   = (float*)(ws + alloc((size_t)N * 4 * 4));
    float* adf   = (float*)(ws + alloc((size_t)N * 4 * 4));
    int* cnt     = (int*)(ws + alloc((size_t)N * CNTS * 4));
    int* flags   = (int*)(ws + alloc(256));
    int* esrc    = (int*)(ws + alloc((size_t)N * SLOT * 4));
    int NBK = (N + 63) >> 6;
    int* bcnt      = (int*)(ws + alloc((size_t)NBK * BCNS * 4));
    unsigned* bdat = (unsigned*)(ws + alloc((size_t)NBK * BCAP * 4));

    int Gg = (N + 63) / 64;                  // gemm tiles (64 rows each)
    int SB = (E + KCH - 1) / KCH;            // scatter chunks
    int NB = SB + Gg;

    k_detect<<<1, 256, 0, stream>>>(idx32, (const unsigned int*)xv, flags);
    k_prep<<<16, 256, 0, stream>>>(d_in[2], d_in[3], d_in[4], d_in[5], flags, Wth, Wtl, attf, biasf);
    if (NBK <= MAXB) {
        hipMemsetAsync(bcnt, 0, (size_t)NBK * BCNS * 4, stream);
        k_gemm_scatter<<<NB, 256, 0, stream>>>(xv, Wth, Wtl, attf, flags, hbf, asf, adf, N,
                                               idx32, idx64, bcnt, bdat, cnt, esrc, E, Gg, SB);
        k_bagg<<<NBK, 256, 0, stream>>>(bdat, bcnt, hbf, asf, adf, idx32, idx64,
                                        biasf, flags, d_out, N, E);
    } else {
        hipMemsetAsync(cnt, 0, (size_t)N * CNTS * 4, stream);
        k_gemm_scatter<<<NB, 256, 0, stream>>>(xv, Wth, Wtl, attf, flags, hbf, asf, adf, N,
                                               idx32, idx64, bcnt, bdat, cnt, esrc, E, Gg, SB);
        k_aggregate<<<(N + 3) / 4, 256, 0, stream>>>(hbf, asf, adf, cnt, esrc, idx32, idx64,
                                                     biasf, flags, d_out, N, E);
    }
}

// Round 7
// 273.640 us; speedup vs baseline: 1.0134x; 1.0134x over previous
//
#include <hip/hip_runtime.h>
#include <stdint.h>

// ---------------------------------------------------------------------------
// GAT layer, dtype-adaptive (probed: fp32 inputs, int32 edge_index, bf16 out).
//   fused:  h = x@W via split-f16 MFMA (fp32-grade), attn dots in epilogue
//           [blocks SB..SB+Gg)]
//           bucketed scatter: 64-node buckets, PER-WAVE LDS histograms +
//           one device atomic per (block,bucket) run-claim (bcnt line-padded
//           64B/bucket), per-wave cursor sub-runs, KCH=8192 [blocks 0..SB)]
//   bagg:   fused demux+aggregate, one block per bucket. Per node the load
//           schedule is PINNED with volatile inline asm + counted
//           s_waitcnt vmcnt(N) + sched_barrier(0): issue asf/adf dwordx4,
//           then all 8*NB h-row dwords, softmax+butterfly under the loads,
//           per-batch counted drains. psh transposed [head][item] so q reads
//           are ds_read_b128 broadcasts. (R6's C-level prefetch was sunk by
//           the compiler -- VGPR 56->48 proved it.)
//   legacy (N > 131072): per-edge scatter into cnt/esrc + old k_aggregate.
// ---------------------------------------------------------------------------

#define SLOT 64
#define CNTS 16    // counter stride in ints (legacy path)
#define BCNS 16    // bcnt stride in ints = one 64B line per bucket
#define BCAP 1536  // bucket capacity (entries); avg fill 1024, ~16 sigma slack
#define MAXB 2048  // max buckets (N <= 131072); 4 per-wave hists = 32KB LDS
#define KCH  8192  // edges per scatter chunk

typedef __attribute__((ext_vector_type(8))) _Float16 h8;
typedef __attribute__((ext_vector_type(4))) float    f4x;

__device__ __forceinline__ float b2f(unsigned short u) {
    union { unsigned int i; float f; } v; v.i = ((unsigned int)u) << 16; return v.f;
}
__device__ __forceinline__ unsigned short f2b(float f) {
    union { float f; unsigned int i; } v; v.f = f;
    unsigned int i = v.i;
    unsigned int r = (i + 0x7FFFu + ((i >> 16) & 1u)) >> 16;  // RNE
    return (unsigned short)r;
}
__device__ __forceinline__ unsigned short f2h(float f) {
    union { _Float16 h; unsigned short u; } v; v.h = (_Float16)f; return v.u;
}
__device__ __forceinline__ float h2f(unsigned short u) {
    union { _Float16 h; unsigned short u; } v; v.u = u; return (float)v.h;
}

// --- 0. dtype probes --------------------------------------------------------
__global__ void k_detect(const int* __restrict__ eidx, const unsigned int* __restrict__ xw,
                         int* flags) {
    __shared__ int nz, bf;
    if (threadIdx.x == 0) { nz = 0; bf = 0; }
    __syncthreads();
    int bad = 0;
    for (int i = threadIdx.x; i < 1024; i += 256)
        if (eidx[2 * i + 1] != 0) bad = 1;
    if (bad) atomicOr(&nz, 1);
    int hits = 0;
    for (int i = threadIdx.x; i < 4096; i += 256) {
        unsigned int e = (xw[i] >> 7) & 0xFFu;
        if (e >= 0x60u && e < 0xA0u) ++hits;
    }
    atomicAdd(&bf, hits);
    __syncthreads();
    if (threadIdx.x == 0) {
        flags[0] = (nz == 0) ? 1 : 0;   // 1 => int64 edge_index
        flags[1] = (bf > 3072) ? 1 : 0; // 1 => bf16 float tensors
    }
}

__device__ __forceinline__ int edge_at(const int* idx32, const long long* idx64,
                                       int is64, long long pos) {
    return is64 ? (int)idx64[pos] : idx32[pos];
}

// --- 0b. W^T hi/lo f16 + att/bias fp32 -> ws --------------------------------
__global__ void k_prep(const void* __restrict__ Wv, const void* __restrict__ asv,
                       const void* __restrict__ adv, const void* __restrict__ bv,
                       const int* __restrict__ flags,
                       _Float16* __restrict__ Wth, _Float16* __restrict__ Wtl,
                       float* __restrict__ attf /*256*/, float* __restrict__ biasf /*128*/) {
    int isbf = flags[1];
    int tid = blockIdx.x * 256 + threadIdx.x;
    for (int i = tid; i < 16384; i += gridDim.x * 256) {
        int col = i >> 7, k = i & 127;            // Wt[col][k] = W[k][col]
        float w = isbf ? b2f(((const unsigned short*)Wv)[k * 128 + col])
                       : ((const float*)Wv)[k * 128 + col];
        unsigned short hi = f2h(w);
        unsigned short lo = f2h(w - h2f(hi));
        ((unsigned short*)Wth)[i] = hi;
        ((unsigned short*)Wtl)[i] = lo;
    }
    if (blockIdx.x == 0) {
        for (int i = threadIdx.x; i < 128; i += 256) {
            attf[i]       = isbf ? b2f(((const unsigned short*)asv)[i]) : ((const float*)asv)[i];
            attf[128 + i] = isbf ? b2f(((const unsigned short*)adv)[i]) : ((const float*)adv)[i];
            biasf[i]      = isbf ? b2f(((const unsigned short*)bv)[i]) : ((const float*)bv)[i];
        }
    }
}

// --- 1. fused MFMA GEMM (blocks >= SB) + bucketed scatter (blocks < SB) -----
__global__ __launch_bounds__(256) void k_gemm_scatter(
    const void* __restrict__ xv,
    const _Float16* __restrict__ Wth, const _Float16* __restrict__ Wtl,
    const float* __restrict__ attf, const int* __restrict__ flags,
    unsigned short* __restrict__ hbf, float* __restrict__ asf,
    float* __restrict__ adf, int N,
    const int* __restrict__ idx32, const long long* __restrict__ idx64,
    int* __restrict__ bcnt, unsigned* __restrict__ bdat,
    int* __restrict__ cnt, int* __restrict__ esrc,
    int E, int Gg, int SB) {
    __shared__ unsigned short xsh[64 * 128];   // x hi-plane / scatter hists 0,1
    __shared__ unsigned short xsl[64 * 128];   // x lo-plane / scatter hists 2,3
    int tid = threadIdx.x;
    int bid = blockIdx.x;

    if (bid < SB) {                            // ---- bucketed scatter ----
        int is64 = flags[0];
        int NBK = (N + 63) >> 6;
        long long e0 = (long long)bid * KCH;
        long long e1 = e0 + KCH; if (e1 > E) e1 = E;
        if (e0 >= E) return;

        if (NBK <= MAXB) {
            int wid = tid >> 6;
            int* h0 = (int*)xsh; int* h1 = h0 + MAXB;
            int* h2 = (int*)xsl; int* h3 = h2 + MAXB;
            int* hw = (wid == 0) ? h0 : (wid == 1) ? h1 : (wid == 2) ? h2 : h3;
            for (int i = tid; i < NBK; i += 256) { h0[i] = 0; h1[i] = 0; h2[i] = 0; h3[i] = 0; }
            __syncthreads();
            // pass 1: per-wave chunk histograms (intra-wave RMW only)
            for (long long e = e0 + tid; e < e1; e += 256) {
                int d = is64 ? (int)idx64[(long long)E + e] : idx32[E + e];
                atomicAdd(&hw[d >> 6], 1);
            }
            __syncthreads();
            // claim: ONE device atomic per non-empty bucket (64B-padded line);
            // per-wave sub-runs
            for (int b = tid; b < NBK; b += 256) {
                int c0 = h0[b], c1 = h1[b], c2 = h2[b], c3 = h3[b];
                int t = c0 + c1 + c2 + c3;
                int base = (t > 0) ? atomicAdd(&bcnt[(size_t)b * BCNS], t) : 0;
                h0[b] = base;
                h1[b] = base + c0;
                h2[b] = base + c0 + c1;
                h3[b] = base + c0 + c1 + c2;
            }
            __syncthreads();
            // pass 2: place entries at per-wave LDS cursors
            for (long long e = e0 + tid; e < e1; e += 256) {
                int d, s;
                if (is64) {
                    d = (int)idx64[(long long)E + e]; s = (int)idx64[e];
                } else {
                    d = idx32[E + e]; s = idx32[e];
                }
                int b = d >> 6;
                int p = atomicAdd(&hw[b], 1);
                if (p < BCAP)
                    bdat[(size_t)b * BCAP + p] = (unsigned)s | ((unsigned)(d & 63) << 26);
            }
        } else {
            // legacy per-edge path (host memsets cnt, uses old k_aggregate)
            for (long long e = e0 + tid; e < e1; e += 256) {
                int d = edge_at(idx32, idx64, is64, (long long)E + e);
                int s = edge_at(idx32, idx64, is64, e);
                int p = atomicAdd(&cnt[(size_t)d * CNTS], 1);
                if (p < SLOT) esrc[(size_t)d * SLOT + p] = s;
            }
        }
        return;
    }

    // ---- MFMA GEMM (unchanged) ----
    int rb = bid - SB;
    if (rb >= Gg) return;
    int r0 = rb * 64;
    int isbf = flags[1];
    int w = tid >> 6;            // wave id = head id (owns cols [32w, 32w+32))
    int lane = tid & 63;
    int li = lane & 15;          // fragment row/col index
    int g  = lane >> 4;          // k-group
    int c0 = w * 32;

    h8 Bh[2][4], Bl[2][4];
#pragma unroll
    for (int t = 0; t < 2; ++t)
#pragma unroll
        for (int s = 0; s < 4; ++s) {
            size_t o = (size_t)(c0 + 16 * t + li) * 128 + 32 * s + 8 * g;
            Bh[t][s] = *(const h8*)(Wth + o);
            Bl[t][s] = *(const h8*)(Wtl + o);
        }

#pragma unroll
    for (int it = 0; it < 4; ++it) {
        int idx = it * 2048 + tid * 8;         // 8 elements per thread per iter
        int r = idx >> 7, k = idx & 127;
        int gr = r0 + r; if (gr >= N) gr = N - 1;
        float v[8];
        if (isbf) {
            uint4 raw = *(const uint4*)((const unsigned short*)xv + (size_t)gr * 128 + k);
            v[0] = b2f((unsigned short)(raw.x & 0xFFFFu)); v[1] = b2f((unsigned short)(raw.x >> 16));
            v[2] = b2f((unsigned short)(raw.y & 0xFFFFu)); v[3] = b2f((unsigned short)(raw.y >> 16));
            v[4] = b2f((unsigned short)(raw.z & 0xFFFFu)); v[5] = b2f((unsigned short)(raw.z >> 16));
            v[6] = b2f((unsigned short)(raw.w & 0xFFFFu)); v[7] = b2f((unsigned short)(raw.w >> 16));
        } else {
            const float* xf = (const float*)xv;
            float4 a = *(const float4*)(xf + (size_t)gr * 128 + k);
            float4 b = *(const float4*)(xf + (size_t)gr * 128 + k + 4);
            v[0] = a.x; v[1] = a.y; v[2] = a.z; v[3] = a.w;
            v[4] = b.x; v[5] = b.y; v[6] = b.z; v[7] = b.w;
        }
        uint4 PH, PL;
        unsigned int ph[4], pl[4];
#pragma unroll
        for (int jj = 0; jj < 4; ++jj) {
            unsigned short h0 = f2h(v[2 * jj]), h1 = f2h(v[2 * jj + 1]);
            unsigned short l0 = f2h(v[2 * jj] - h2f(h0));
            unsigned short l1 = f2h(v[2 * jj + 1] - h2f(h1));
            ph[jj] = (unsigned int)h0 | ((unsigned int)h1 << 16);
            pl[jj] = (unsigned int)l0 | ((unsigned int)l1 << 16);
        }
        PH.x = ph[0]; PH.y = ph[1]; PH.z = ph[2]; PH.w = ph[3];
        PL.x = pl[0]; PL.y = pl[1]; PL.z = pl[2]; PL.w = pl[3];
        int off = r * 256 + ((2 * k) ^ ((r & 7) << 4));   // 16B-slot XOR swizzle
        *(uint4*)((char*)xsh + off) = PH;
        *(uint4*)((char*)xsl + off) = PL;
    }
    __syncthreads();

    f4x acc[4][2];
#pragma unroll
    for (int m = 0; m < 4; ++m)
#pragma unroll
        for (int t = 0; t < 2; ++t) acc[m][t] = (f4x){0.f, 0.f, 0.f, 0.f};

#pragma unroll
    for (int s = 0; s < 4; ++s) {
#pragma unroll
        for (int m = 0; m < 4; ++m) {
            int row = 16 * m + li;
            int kb = (32 * s + 8 * g) * 2;
            int off = row * 256 + (kb ^ ((row & 7) << 4));
            h8 ah = *(const h8*)((const char*)xsh + off);
            h8 al = *(const h8*)((const char*)xsl + off);
#pragma unroll
            for (int t = 0; t < 2; ++t) {
                acc[m][t] = __builtin_amdgcn_mfma_f32_16x16x32_f16(ah, Bh[t][s], acc[m][t], 0, 0, 0);
                acc[m][t] = __builtin_amdgcn_mfma_f32_16x16x32_f16(al, Bh[t][s], acc[m][t], 0, 0, 0);
                acc[m][t] = __builtin_amdgcn_mfma_f32_16x16x32_f16(ah, Bl[t][s], acc[m][t], 0, 0, 0);
            }
        }
    }

    // Epilogue 1: attn dots from fp32 acc. C/D: col = li, row = 4*g + reg.
    float at_s0 = attf[c0 + li],       at_s1 = attf[c0 + 16 + li];
    float at_d0 = attf[128 + c0 + li], at_d1 = attf[128 + c0 + 16 + li];
#pragma unroll
    for (int m = 0; m < 4; ++m) {
        float s1v[4], s2v[4];
#pragma unroll
        for (int j = 0; j < 4; ++j) {
            s1v[j] = acc[m][0][j] * at_s0 + acc[m][1][j] * at_s1;
            s2v[j] = acc[m][0][j] * at_d0 + acc[m][1][j] * at_d1;
        }
#pragma unroll
        for (int j = 0; j < 4; ++j) {
#pragma unroll
            for (int msk = 1; msk < 16; msk <<= 1) {
                s1v[j] += __shfl_xor(s1v[j], msk);
                s2v[j] += __shfl_xor(s2v[j], msk);
            }
        }
        if (li == 0) {
#pragma unroll
            for (int j = 0; j < 4; ++j) {
                int gr = r0 + 16 * m + 4 * g + j;
                if (gr < N) {
                    asf[(size_t)gr * 4 + w] = s1v[j];
                    adf[(size_t)gr * 4 + w] = s2v[j];
                }
            }
        }
    }

    // Epilogue 2: h -> bf16 via LDS (reuse hi-plane) for coalesced store.
    __syncthreads();
#pragma unroll
    for (int m = 0; m < 4; ++m)
#pragma unroll
        for (int t = 0; t < 2; ++t)
#pragma unroll
            for (int j = 0; j < 4; ++j)
                xsh[(16 * m + 4 * g + j) * 128 + c0 + 16 * t + li] = f2b(acc[m][t][j]);
    __syncthreads();
#pragma unroll
    for (int it = 0; it < 4; ++it) {
        int u = it * 2048 + tid * 8;
        int r = u >> 7, k = u & 127;
        int gr = r0 + r;
        if (gr < N)
            *(uint4*)(hbf + (size_t)gr * 128 + k) = *(const uint4*)(xsh + u);
    }
}

// --- 2. fused demux + aggregate: one block per 64-node bucket ---------------
// Fast path (deg<=31): asm-pinned load schedule, counted vmcnt drains.
// psh layout: [head*64 + item]; item 0 = self-loop, item k = edge k-1.
template <int NB>
__device__ __forceinline__ void agg_node(
    int n, int dl, int deg, int lane, int head,
    const int lslot[64][SLOT], float* psh,
    const unsigned short* __restrict__ hbf,
    const float* __restrict__ asf, const float* __restrict__ adf,
    float& a0o, float& a1o, float& invho) {
    // (1) issue asf/adf row loads (oldest in vmcnt queue)
    int sl = (lane == 0) ? n : ((lane <= deg) ? lslot[dl][lane - 1] : n);
    float4 av, adv;
    asm volatile("global_load_dwordx4 %0, %1, off"
                 : "=v"(av) : "v"((const void*)(asf + (size_t)sl * 4)));
    asm volatile("global_load_dwordx4 %0, %1, off"
                 : "=v"(adv) : "v"((const void*)(adf + (size_t)n * 4)));
    // (2) issue ALL h-row gathers (volatile asm keeps mutual order; compiler
    //     cannot sink these past the softmax like it did with C loads)
    unsigned vv[NB * 8];
#pragma unroll
    for (int it = 0; it < NB * 8; ++it) {
        int s = (it == 0) ? n : ((it <= deg) ? lslot[dl][it - 1] : n);
        asm volatile("global_load_dword %0, %1, off"
                     : "=v"(vv[it]) : "v"((const void*)(hbf + (size_t)s * 128 + 2 * lane)));
    }
    // (3) wait only for av/adv (2 oldest); h loads stay in flight
    asm volatile("s_waitcnt vmcnt(%0)" :: "n"(NB * 8));
    __builtin_amdgcn_sched_barrier(0);

    float p0 = 0.f, p1 = 0.f, p2 = 0.f, p3 = 0.f;
    if (lane <= deg) {
        float e0 = av.x + adv.x; e0 = fmaxf(e0, 0.2f * e0); p0 = __expf(e0);
        float e1 = av.y + adv.y; e1 = fmaxf(e1, 0.2f * e1); p1 = __expf(e1);
        float e2 = av.z + adv.z; e2 = fmaxf(e2, 0.2f * e2); p2 = __expf(e2);
        float e3 = av.w + adv.w; e3 = fmaxf(e3, 0.2f * e3); p3 = __expf(e3);
    }
    psh[0 * 64 + lane] = p0; psh[1 * 64 + lane] = p1;   // zeros beyond deg
    psh[2 * 64 + lane] = p2; psh[3 * 64 + lane] = p3;   //  -> padded q = 0
    __builtin_amdgcn_wave_barrier();
    asm volatile("s_waitcnt lgkmcnt(0)" ::: "memory");
    __builtin_amdgcn_wave_barrier();

    float ps0 = p0, ps1 = p1, ps2 = p2, ps3 = p3;
#pragma unroll
    for (int m = 1; m < 64; m <<= 1) {     // 64-lane butterfly denom
        ps0 += __shfl_xor(ps0, m);
        ps1 += __shfl_xor(ps1, m);
        ps2 += __shfl_xor(ps2, m);
        ps3 += __shfl_xor(ps3, m);
    }
    float den = head == 0 ? ps0 : head == 1 ? ps1 : head == 2 ? ps2 : ps3;
    invho = 1.0f / (den + 1e-16f);

    // (4) consume with counted drains; q via b128 broadcast reads
    float a0 = 0.f, a1 = 0.f;
#pragma unroll
    for (int bi = 0; bi < NB; ++bi) {
        asm volatile("s_waitcnt vmcnt(%0)" :: "n"(8 * (NB - 1 - bi)));
        __builtin_amdgcn_sched_barrier(0);
        float4 qa = *(const float4*)(psh + head * 64 + bi * 8);
        float4 qb = *(const float4*)(psh + head * 64 + bi * 8 + 4);
#pragma unroll
        for (int k2 = 0; k2 < 8; ++k2) {
            float q = k2 < 4 ? qa[k2] : qb[k2 - 4];
            unsigned v = vv[bi * 8 + k2];
            a0 += q * b2f((unsigned short)v);
            a1 += q * b2f((unsigned short)(v >> 16));
        }
    }
    a0o = a0; a1o = a1;
}

__global__ __launch_bounds__(256) void k_bagg(
    const unsigned* __restrict__ bdat, const int* __restrict__ bcnt,
    const unsigned short* __restrict__ hbf,
    const float* __restrict__ asf, const float* __restrict__ adf,
    const int* __restrict__ idx32, const long long* __restrict__ idx64,
    const float* __restrict__ biasf, const int* __restrict__ flags,
    void* __restrict__ outv, int N, int E) {
    __shared__ int   lcnt[64];
    __shared__ int   lslot[64][SLOT];          // 16KB
    __shared__ float p_all[4][SLOT * 4];       // 4KB, per-wave transient
    int b = blockIdx.x, tid = threadIdx.x;
    int wid = tid >> 6, lane = tid & 63, head = lane >> 4;

    if (tid < 64) lcnt[tid] = 0;
    __syncthreads();
    int mm = bcnt[(size_t)b * BCNS];
    int ovf = (mm > BCAP);
    if (mm > BCAP) mm = BCAP;
    for (int i = tid; i < mm; i += 256) {      // demux bucket -> LDS CSR
        unsigned e = bdat[(size_t)b * BCAP + i];
        int dl = (int)(e >> 26);
        int p = atomicAdd(&lcnt[dl], 1);
        if (p < SLOT) lslot[dl][p] = (int)(e & 0x03FFFFFFu);
    }
    __syncthreads();

    float b0 = biasf[2 * lane], b1 = biasf[2 * lane + 1];
    float* psh = p_all[wid];
    int isbf = flags[1];
    int is64 = flags[0];

    for (int u = 0; u < 16; ++u) {             // 16 nodes per wave, no block sync
        int dl = wid * 16 + u;
        int n = (b << 6) + dl;
        if (n >= N) break;                     // wave-uniform
        int deg = lcnt[dl];
        bool fb = ovf || (deg > SLOT - 1);
        float a0 = 0.f, a1 = 0.f, invh = 0.f;

        if (!fb && deg <= 31) {
            int nb = (deg + 8) >> 3;           // ceil((deg+1)/8), wave-uniform
            switch (nb) {
                case 1: agg_node<1>(n, dl, deg, lane, head, lslot, psh, hbf, asf, adf, a0, a1, invh); break;
                case 2: agg_node<2>(n, dl, deg, lane, head, lslot, psh, hbf, asf, adf, a0, a1, invh); break;
                case 3: agg_node<3>(n, dl, deg, lane, head, lslot, psh, hbf, asf, adf, a0, a1, invh); break;
                default: agg_node<4>(n, dl, deg, lane, head, lslot, psh, hbf, asf, adf, a0, a1, invh); break;
            }
        } else if (!fb) {
            // generic path (32 <= deg <= 63): plain C, sequential batches.
            float4 adv = *(const float4*)(adf + (size_t)n * 4);
            int sl = (lane == 0) ? n : ((lane <= deg) ? lslot[dl][lane - 1] : n);
            float4 av = *(const float4*)(asf + (size_t)sl * 4);
            float p0 = 0.f, p1 = 0.f, p2 = 0.f, p3 = 0.f;
            if (lane <= deg) {
                float e0 = av.x + adv.x; e0 = fmaxf(e0, 0.2f * e0); p0 = __expf(e0);
                float e1 = av.y + adv.y; e1 = fmaxf(e1, 0.2f * e1); p1 = __expf(e1);
                float e2 = av.z + adv.z; e2 = fmaxf(e2, 0.2f * e2); p2 = __expf(e2);
                float e3 = av.w + adv.w; e3 = fmaxf(e3, 0.2f * e3); p3 = __expf(e3);
            }
            psh[0 * 64 + lane] = p0; psh[1 * 64 + lane] = p1;
            psh[2 * 64 + lane] = p2; psh[3 * 64 + lane] = p3;
            __builtin_amdgcn_wave_barrier();
            asm volatile("s_waitcnt lgkmcnt(0)" ::: "memory");
            __builtin_amdgcn_wave_barrier();
            float ps0 = p0, ps1 = p1, ps2 = p2, ps3 = p3;
#pragma unroll
            for (int m = 1; m < 64; m <<= 1) {
                ps0 += __shfl_xor(ps0, m);
                ps1 += __shfl_xor(ps1, m);
                ps2 += __shfl_xor(ps2, m);
                ps3 += __shfl_xor(ps3, m);
            }
            float den = head == 0 ? ps0 : head == 1 ? ps1 : head == 2 ? ps2 : ps3;
            invh = 1.0f / (den + 1e-16f);
            int nb = (deg + 8) >> 3;
            for (int bi = 0; bi < nb; ++bi) {
                unsigned vt[8];
#pragma unroll
                for (int k2 = 0; k2 < 8; ++k2) {
                    int it = bi * 8 + k2;
                    int s = (it == 0) ? n : ((it <= deg) ? lslot[dl][it - 1] : n);
                    vt[k2] = *(const unsigned int*)(hbf + (size_t)s * 128 + 2 * lane);
                }
                float4 qa = *(const float4*)(psh + head * 64 + bi * 8);
                float4 qb = *(const float4*)(psh + head * 64 + bi * 8 + 4);
#pragma unroll
                for (int k2 = 0; k2 < 8; ++k2) {
                    float q = k2 < 4 ? qa[k2] : qb[k2 - 4];
                    a0 += q * b2f((unsigned short)vt[k2]);
                    a1 += q * b2f((unsigned short)(vt[k2] >> 16));
                }
            }
        } else {
            // parachute: deg >= SLOT or bucket overflow. Exact full rescan.
            float4 adv = *(const float4*)(adf + (size_t)n * 4);
            float adh = head == 0 ? adv.x : head == 1 ? adv.y : head == 2 ? adv.z : adv.w;
            float den = 0.f;
            {   // self-loop
                float ev = asf[(size_t)n * 4 + head] + adh; ev = fmaxf(ev, 0.2f * ev);
                float p = __expf(ev);
                unsigned int v = *(const unsigned int*)(hbf + (size_t)n * 128 + 2 * lane);
                den += p;
                a0 += p * b2f((unsigned short)v);
                a1 += p * b2f((unsigned short)(v >> 16));
            }
            for (int e = 0; e < E; ++e) {
                int d = edge_at(idx32, idx64, is64, (long long)E + e);
                if (d == n) {
                    int s = edge_at(idx32, idx64, is64, e);
                    float ev = asf[(size_t)s * 4 + head] + adh; ev = fmaxf(ev, 0.2f * ev);
                    float p = __expf(ev);
                    unsigned int v = *(const unsigned int*)(hbf + (size_t)s * 128 + 2 * lane);
                    den += p;
                    a0 += p * b2f((unsigned short)v);
                    a1 += p * b2f((unsigned short)(v >> 16));
                }
            }
            invh = 1.0f / (den + 1e-16f);
        }

        a0 = a0 * invh + b0;
        a1 = a1 * invh + b1;
        if (isbf) {
            unsigned int pk = (unsigned int)f2b(a0) | ((unsigned int)f2b(a1) << 16);
            ((unsigned int*)outv)[(size_t)n * 64 + lane] = pk;
        } else {
            float2 f2; f2.x = a0; f2.y = a1;
            *(float2*)((float*)outv + (size_t)n * 128 + 2 * lane) = f2;
        }
        __builtin_amdgcn_wave_barrier();
    }
}

// --- 2L. legacy aggregate (NBK > MAXB only): one wave per node --------------
__global__ __launch_bounds__(256) void k_aggregate(
    const unsigned short* __restrict__ hbf,
    const float* __restrict__ asf, const float* __restrict__ adf,
    const int* __restrict__ cnt, const int* __restrict__ esrc,
    const int* __restrict__ idx32, const long long* __restrict__ idx64,
    const float* __restrict__ biasf, const int* __restrict__ flags,
    void* __restrict__ outv, int N, int E) {
    __shared__ float p_sh_all[4][SLOT * 4];
    __shared__ int   s_sh_all[4][SLOT];
    int wid = threadIdx.x >> 6;
    int lane = threadIdx.x & 63;
    int n = blockIdx.x * 4 + wid;
    if (n >= N) n = N - 1;                     // tail waves redo a node (benign)
    float* p_sh = p_sh_all[wid];
    int*   s_sh = s_sh_all[wid];
    int head = lane >> 4;

    int deg = cnt[(size_t)n * CNTS];           // edges, excl. self-loop
    float4 adv = *(const float4*)(adf + (size_t)n * 4);
    bool fb = (deg > SLOT - 1);                // total deg+1 must fit in 64

    float p0 = 0.f, p1 = 0.f, p2 = 0.f, p3 = 0.f;
    if (!fb && lane <= deg) {                  // phase 1: one item per lane
        int s = (lane == 0) ? n : esrc[(size_t)n * SLOT + lane - 1];
        float4 av = *(const float4*)(asf + (size_t)s * 4);
        float e0 = av.x + adv.x; e0 = fmaxf(e0, 0.2f * e0); p0 = __expf(e0);
        float e1 = av.y + adv.y; e1 = fmaxf(e1, 0.2f * e1); p1 = __expf(e1);
        float e2 = av.z + adv.z; e2 = fmaxf(e2, 0.2f * e2); p2 = __expf(e2);
        float e3 = av.w + adv.w; e3 = fmaxf(e3, 0.2f * e3); p3 = __expf(e3);
        s_sh[lane] = s;
        p_sh[lane * 4 + 0] = p0; p_sh[lane * 4 + 1] = p1;
        p_sh[lane * 4 + 2] = p2; p_sh[lane * 4 + 3] = p3;
    }
    __syncthreads();

    float b0 = biasf[2 * lane], b1 = biasf[2 * lane + 1];
    float a0 = 0.f, a1 = 0.f, invh;

    if (!fb) {
        float ps0 = p0, ps1 = p1, ps2 = p2, ps3 = p3;
#pragma unroll
        for (int m = 1; m < 64; m <<= 1) {     // 64-lane butterfly
            ps0 += __shfl_xor(ps0, m);
            ps1 += __shfl_xor(ps1, m);
            ps2 += __shfl_xor(ps2, m);
            ps3 += __shfl_xor(ps3, m);
        }
        float den = head == 0 ? ps0 : head == 1 ? ps1 : head == 2 ? ps2 : ps3;
        invh = 1.0f / (den + 1e-16f);

        int tot = deg + 1;
        int i = 0;
        for (; i + 3 < tot; i += 4) {          // 4 row-gathers in flight
            int s0 = s_sh[i], s1 = s_sh[i + 1], s2 = s_sh[i + 2], s3 = s_sh[i + 3];
            float q0 = p_sh[i * 4 + head],       q1 = p_sh[(i + 1) * 4 + head];
            float q2 = p_sh[(i + 2) * 4 + head], q3 = p_sh[(i + 3) * 4 + head];
            unsigned int v0 = *(const unsigned int*)(hbf + (size_t)s0 * 128 + 2 * lane);
            unsigned int v1 = *(const unsigned int*)(hbf + (size_t)s1 * 128 + 2 * lane);
            unsigned int v2 = *(const unsigned int*)(hbf + (size_t)s2 * 128 + 2 * lane);
            unsigned int v3 = *(const unsigned int*)(hbf + (size_t)s3 * 128 + 2 * lane);
            a0 += q0 * b2f((unsigned short)v0) + q1 * b2f((unsigned short)v1)
                + q2 * b2f((unsigned short)v2) + q3 * b2f((unsigned short)v3);
            a1 += q0 * b2f((unsigned short)(v0 >> 16)) + q1 * b2f((unsigned short)(v1 >> 16))
                + q2 * b2f((unsigned short)(v2 >> 16)) + q3 * b2f((unsigned short)(v3 >> 16));
        }
        for (; i < tot; ++i) {
            int s0 = s_sh[i];
            float q0 = p_sh[i * 4 + head];
            unsigned int v0 = *(const unsigned int*)(hbf + (size_t)s0 * 128 + 2 * lane);
            a0 += q0 * b2f((unsigned short)v0);
            a1 += q0 * b2f((unsigned short)(v0 >> 16));
        }
    } else {
        int is64 = flags[0];
        float adh = head == 0 ? adv.x : head == 1 ? adv.y : head == 2 ? adv.z : adv.w;
        float den = 0.f;
        {   // self-loop
            float ev = asf[(size_t)n * 4 + head] + adh; ev = fmaxf(ev, 0.2f * ev);
            float p = __expf(ev);
            unsigned int v = *(const unsigned int*)(hbf + (size_t)n * 128 + 2 * lane);
            den += p;
            a0 += p * b2f((unsigned short)v);
            a1 += p * b2f((unsigned short)(v >> 16));
        }
        for (int e = 0; e < E; ++e) {
            int d = edge_at(idx32, idx64, is64, (long long)E + e);
            if (d == n) {
                int s = edge_at(idx32, idx64, is64, e);
                float ev = asf[(size_t)s * 4 + head] + adh; ev = fmaxf(ev, 0.2f * ev);
                float p = __expf(ev);
                unsigned int v = *(const unsigned int*)(hbf + (size_t)s * 128 + 2 * lane);
                den += p;
                a0 += p * b2f((unsigned short)v);
                a1 += p * b2f((unsigned short)(v >> 16));
            }
        }
        invh = 1.0f / (den + 1e-16f);
    }

    a0 = a0 * invh + b0;
    a1 = a1 * invh + b1;
    if (flags[1]) {
        unsigned int pk = (unsigned int)f2b(a0) | ((unsigned int)f2b(a1) << 16);
        ((unsigned int*)outv)[(size_t)n * 64 + lane] = pk;
    } else {
        float2 f2; f2.x = a0; f2.y = a1;
        *(float2*)((float*)outv + (size_t)n * 128 + 2 * lane) = f2;
    }
}

// ---------------------------------------------------------------------------
extern "C" void kernel_launch(void* const* d_in, const int* in_sizes, int n_in,
                              void* d_out, int out_size, void* d_ws, size_t ws_size,
                              hipStream_t stream) {
    const void*      xv    = d_in[0];
    const int*       idx32 = (const int*)d_in[1];
    const long long* idx64 = (const long long*)d_in[1];

    int N = in_sizes[0] / 128;
    int E = in_sizes[1] / 2;

    char* ws = (char*)d_ws;
    size_t o = 0;
    auto alloc = [&](size_t bytes) {
        size_t r = o; o += (bytes + 255) & ~(size_t)255; return r;
    };
    unsigned short* hbf = (unsigned short*)(ws + alloc((size_t)N * 128 * 2));
    _Float16* Wth = (_Float16*)(ws + alloc(16384 * 2));
    _Float16* Wtl = (_Float16*)(ws + alloc(16384 * 2));
    float* attf  = (float*)(ws + alloc(256 * 4));
    float* biasf = (float*)(ws + alloc(128 * 4));
    float* asf   = (float*)(ws + alloc((size_t)N * 4 * 4));
    float* adf   = (float*)(ws + alloc((size_t)N * 4 * 4));
    int* cnt     = (int*)(ws + alloc((size_t)N * CNTS * 4));
    int* flags   = (int*)(ws + alloc(256));
    int* esrc    = (int*)(ws + alloc((size_t)N * SLOT * 4));
    int NBK = (N + 63) >> 6;
    int* bcnt      = (int*)(ws + alloc((size_t)NBK * BCNS * 4));
    unsigned* bdat = (unsigned*)(ws + alloc((size_t)NBK * BCAP * 4));

    int Gg = (N + 63) / 64;                  // gemm tiles (64 rows each)
    int SB = (E + KCH - 1) / KCH;            // scatter chunks
    int NB = SB + Gg;

    k_detect<<<1, 256, 0, stream>>>(idx32, (const unsigned int*)xv, flags);
    k_prep<<<16, 256, 0, stream>>>(d_in[2], d_in[3], d_in[4], d_in[5], flags, Wth, Wtl, attf, biasf);
    if (NBK <= MAXB) {
        hipMemsetAsync(bcnt, 0, (size_t)NBK * BCNS * 4, stream);
        k_gemm_scatter<<<NB, 256, 0, stream>>>(xv, Wth, Wtl, attf, flags, hbf, asf, adf, N,
                                               idx32, idx64, bcnt, bdat, cnt, esrc, E, Gg, SB);
        k_bagg<<<NBK, 256, 0, stream>>>(bdat, bcnt, hbf, asf, adf, idx32, idx64,
                                        biasf, flags, d_out, N, E);
    } else {
        hipMemsetAsync(cnt, 0, (size_t)N * CNTS * 4, stream);
        k_gemm_scatter<<<NB, 256, 0, stream>>>(xv, Wth, Wtl, attf, flags, hbf, asf, adf, N,
                                               idx32, idx64, bcnt, bdat, cnt, esrc, E, Gg, SB);
        k_aggregate<<<(N + 3) / 4, 256, 0, stream>>>(hbf, asf, adf, cnt, esrc, idx32, idx64,
                                                     biasf, flags, d_out, N, E);
    }
}

// Round 8
// 253.977 us; speedup vs baseline: 1.0919x; 1.0774x over previous
//
#include <hip/hip_runtime.h>
#include <stdint.h>

// ---------------------------------------------------------------------------
// GAT layer, dtype-adaptive (probed: fp32 inputs, int32 edge_index, bf16 out).
//   fused:  h = x@W via split-f16 MFMA (fp32-grade), attn dots in epilogue
//           [blocks SB..SB+Gg)]
//           bucketed scatter: 64-node buckets, PER-WAVE LDS histograms +
//           one device atomic per (block,bucket) run-claim (bcnt line-padded
//           64B/bucket), per-wave cursor sub-runs, KCH=8192 [blocks 0..SB)]
//   bagg:   fused demux+aggregate, one block per bucket. PAIRED gathers:
//           lanes 0-31 = even item's row, lanes 32-63 = odd item's row,
//           dwordx2/lane (4 ch) -> half the VMEM instructions at the same
//           transaction count; final shfl_xor(32) merges halves. Load
//           schedule asm-pinned (issue asf/adf, then all h rows, softmax
//           under the loads, counted vmcnt drains). psh stride 68 floats
//           (bank-conflict-free; R7's stride-64 cost 2.5M conflicts).
//   legacy (N > 131072): per-edge scatter into cnt/esrc + old k_aggregate.
// ---------------------------------------------------------------------------

#define SLOT 64
#define CNTS 16    // counter stride in ints (legacy path)
#define BCNS 16    // bcnt stride in ints = one 64B line per bucket
#define BCAP 1536  // bucket capacity (entries); avg fill 1024, ~16 sigma slack
#define MAXB 2048  // max buckets (N <= 131072); 4 per-wave hists = 32KB LDS
#define KCH  8192  // edges per scatter chunk
#define PST  68    // psh stride in floats (272B -> banks rotate 4 per head)

typedef __attribute__((ext_vector_type(8))) _Float16 h8;
typedef __attribute__((ext_vector_type(4))) float    f4x;
typedef __attribute__((ext_vector_type(2))) unsigned u32x2;

__device__ __forceinline__ float b2f(unsigned short u) {
    union { unsigned int i; float f; } v; v.i = ((unsigned int)u) << 16; return v.f;
}
__device__ __forceinline__ unsigned short f2b(float f) {
    union { float f; unsigned int i; } v; v.f = f;
    unsigned int i = v.i;
    unsigned int r = (i + 0x7FFFu + ((i >> 16) & 1u)) >> 16;  // RNE
    return (unsigned short)r;
}
__device__ __forceinline__ unsigned short f2h(float f) {
    union { _Float16 h; unsigned short u; } v; v.h = (_Float16)f; return v.u;
}
__device__ __forceinline__ float h2f(unsigned short u) {
    union { _Float16 h; unsigned short u; } v; v.u = u; return (float)v.h;
}

// --- 0. dtype probes --------------------------------------------------------
__global__ void k_detect(const int* __restrict__ eidx, const unsigned int* __restrict__ xw,
                         int* flags) {
    __shared__ int nz, bf;
    if (threadIdx.x == 0) { nz = 0; bf = 0; }
    __syncthreads();
    int bad = 0;
    for (int i = threadIdx.x; i < 1024; i += 256)
        if (eidx[2 * i + 1] != 0) bad = 1;
    if (bad) atomicOr(&nz, 1);
    int hits = 0;
    for (int i = threadIdx.x; i < 4096; i += 256) {
        unsigned int e = (xw[i] >> 7) & 0xFFu;
        if (e >= 0x60u && e < 0xA0u) ++hits;
    }
    atomicAdd(&bf, hits);
    __syncthreads();
    if (threadIdx.x == 0) {
        flags[0] = (nz == 0) ? 1 : 0;   // 1 => int64 edge_index
        flags[1] = (bf > 3072) ? 1 : 0; // 1 => bf16 float tensors
    }
}

__device__ __forceinline__ int edge_at(const int* idx32, const long long* idx64,
                                       int is64, long long pos) {
    return is64 ? (int)idx64[pos] : idx32[pos];
}

// --- 0b. W^T hi/lo f16 + att/bias fp32 -> ws --------------------------------
__global__ void k_prep(const void* __restrict__ Wv, const void* __restrict__ asv,
                       const void* __restrict__ adv, const void* __restrict__ bv,
                       const int* __restrict__ flags,
                       _Float16* __restrict__ Wth, _Float16* __restrict__ Wtl,
                       float* __restrict__ attf /*256*/, float* __restrict__ biasf /*128*/) {
    int isbf = flags[1];
    int tid = blockIdx.x * 256 + threadIdx.x;
    for (int i = tid; i < 16384; i += gridDim.x * 256) {
        int col = i >> 7, k = i & 127;            // Wt[col][k] = W[k][col]
        float w = isbf ? b2f(((const unsigned short*)Wv)[k * 128 + col])
                       : ((const float*)Wv)[k * 128 + col];
        unsigned short hi = f2h(w);
        unsigned short lo = f2h(w - h2f(hi));
        ((unsigned short*)Wth)[i] = hi;
        ((unsigned short*)Wtl)[i] = lo;
    }
    if (blockIdx.x == 0) {
        for (int i = threadIdx.x; i < 128; i += 256) {
            attf[i]       = isbf ? b2f(((const unsigned short*)asv)[i]) : ((const float*)asv)[i];
            attf[128 + i] = isbf ? b2f(((const unsigned short*)adv)[i]) : ((const float*)adv)[i];
            biasf[i]      = isbf ? b2f(((const unsigned short*)bv)[i]) : ((const float*)bv)[i];
        }
    }
}

// --- 1. fused MFMA GEMM (blocks >= SB) + bucketed scatter (blocks < SB) -----
__global__ __launch_bounds__(256) void k_gemm_scatter(
    const void* __restrict__ xv,
    const _Float16* __restrict__ Wth, const _Float16* __restrict__ Wtl,
    const float* __restrict__ attf, const int* __restrict__ flags,
    unsigned short* __restrict__ hbf, float* __restrict__ asf,
    float* __restrict__ adf, int N,
    const int* __restrict__ idx32, const long long* __restrict__ idx64,
    int* __restrict__ bcnt, unsigned* __restrict__ bdat,
    int* __restrict__ cnt, int* __restrict__ esrc,
    int E, int Gg, int SB) {
    __shared__ unsigned short xsh[64 * 128];   // x hi-plane / scatter hists 0,1
    __shared__ unsigned short xsl[64 * 128];   // x lo-plane / scatter hists 2,3
    int tid = threadIdx.x;
    int bid = blockIdx.x;

    if (bid < SB) {                            // ---- bucketed scatter ----
        int is64 = flags[0];
        int NBK = (N + 63) >> 6;
        long long e0 = (long long)bid * KCH;
        long long e1 = e0 + KCH; if (e1 > E) e1 = E;
        if (e0 >= E) return;

        if (NBK <= MAXB) {
            int wid = tid >> 6;
            int* h0 = (int*)xsh; int* h1 = h0 + MAXB;
            int* h2 = (int*)xsl; int* h3 = h2 + MAXB;
            int* hw = (wid == 0) ? h0 : (wid == 1) ? h1 : (wid == 2) ? h2 : h3;
            for (int i = tid; i < NBK; i += 256) { h0[i] = 0; h1[i] = 0; h2[i] = 0; h3[i] = 0; }
            __syncthreads();
            // pass 1: per-wave chunk histograms (intra-wave RMW only)
            for (long long e = e0 + tid; e < e1; e += 256) {
                int d = is64 ? (int)idx64[(long long)E + e] : idx32[E + e];
                atomicAdd(&hw[d >> 6], 1);
            }
            __syncthreads();
            // claim: ONE device atomic per non-empty bucket (64B-padded line);
            // per-wave sub-runs
            for (int b = tid; b < NBK; b += 256) {
                int c0 = h0[b], c1 = h1[b], c2 = h2[b], c3 = h3[b];
                int t = c0 + c1 + c2 + c3;
                int base = (t > 0) ? atomicAdd(&bcnt[(size_t)b * BCNS], t) : 0;
                h0[b] = base;
                h1[b] = base + c0;
                h2[b] = base + c0 + c1;
                h3[b] = base + c0 + c1 + c2;
            }
            __syncthreads();
            // pass 2: place entries at per-wave LDS cursors
            for (long long e = e0 + tid; e < e1; e += 256) {
                int d, s;
                if (is64) {
                    d = (int)idx64[(long long)E + e]; s = (int)idx64[e];
                } else {
                    d = idx32[E + e]; s = idx32[e];
                }
                int b = d >> 6;
                int p = atomicAdd(&hw[b], 1);
                if (p < BCAP)
                    bdat[(size_t)b * BCAP + p] = (unsigned)s | ((unsigned)(d & 63) << 26);
            }
        } else {
            // legacy per-edge path (host memsets cnt, uses old k_aggregate)
            for (long long e = e0 + tid; e < e1; e += 256) {
                int d = edge_at(idx32, idx64, is64, (long long)E + e);
                int s = edge_at(idx32, idx64, is64, e);
                int p = atomicAdd(&cnt[(size_t)d * CNTS], 1);
                if (p < SLOT) esrc[(size_t)d * SLOT + p] = s;
            }
        }
        return;
    }

    // ---- MFMA GEMM (unchanged) ----
    int rb = bid - SB;
    if (rb >= Gg) return;
    int r0 = rb * 64;
    int isbf = flags[1];
    int w = tid >> 6;            // wave id = head id (owns cols [32w, 32w+32))
    int lane = tid & 63;
    int li = lane & 15;          // fragment row/col index
    int g  = lane >> 4;          // k-group
    int c0 = w * 32;

    h8 Bh[2][4], Bl[2][4];
#pragma unroll
    for (int t = 0; t < 2; ++t)
#pragma unroll
        for (int s = 0; s < 4; ++s) {
            size_t o = (size_t)(c0 + 16 * t + li) * 128 + 32 * s + 8 * g;
            Bh[t][s] = *(const h8*)(Wth + o);
            Bl[t][s] = *(const h8*)(Wtl + o);
        }

#pragma unroll
    for (int it = 0; it < 4; ++it) {
        int idx = it * 2048 + tid * 8;         // 8 elements per thread per iter
        int r = idx >> 7, k = idx & 127;
        int gr = r0 + r; if (gr >= N) gr = N - 1;
        float v[8];
        if (isbf) {
            uint4 raw = *(const uint4*)((const unsigned short*)xv + (size_t)gr * 128 + k);
            v[0] = b2f((unsigned short)(raw.x & 0xFFFFu)); v[1] = b2f((unsigned short)(raw.x >> 16));
            v[2] = b2f((unsigned short)(raw.y & 0xFFFFu)); v[3] = b2f((unsigned short)(raw.y >> 16));
            v[4] = b2f((unsigned short)(raw.z & 0xFFFFu)); v[5] = b2f((unsigned short)(raw.z >> 16));
            v[6] = b2f((unsigned short)(raw.w & 0xFFFFu)); v[7] = b2f((unsigned short)(raw.w >> 16));
        } else {
            const float* xf = (const float*)xv;
            float4 a = *(const float4*)(xf + (size_t)gr * 128 + k);
            float4 b = *(const float4*)(xf + (size_t)gr * 128 + k + 4);
            v[0] = a.x; v[1] = a.y; v[2] = a.z; v[3] = a.w;
            v[4] = b.x; v[5] = b.y; v[6] = b.z; v[7] = b.w;
        }
        uint4 PH, PL;
        unsigned int ph[4], pl[4];
#pragma unroll
        for (int jj = 0; jj < 4; ++jj) {
            unsigned short h0 = f2h(v[2 * jj]), h1 = f2h(v[2 * jj + 1]);
            unsigned short l0 = f2h(v[2 * jj] - h2f(h0));
            unsigned short l1 = f2h(v[2 * jj + 1] - h2f(h1));
            ph[jj] = (unsigned int)h0 | ((unsigned int)h1 << 16);
            pl[jj] = (unsigned int)l0 | ((unsigned int)l1 << 16);
        }
        PH.x = ph[0]; PH.y = ph[1]; PH.z = ph[2]; PH.w = ph[3];
        PL.x = pl[0]; PL.y = pl[1]; PL.z = pl[2]; PL.w = pl[3];
        int off = r * 256 + ((2 * k) ^ ((r & 7) << 4));   // 16B-slot XOR swizzle
        *(uint4*)((char*)xsh + off) = PH;
        *(uint4*)((char*)xsl + off) = PL;
    }
    __syncthreads();

    f4x acc[4][2];
#pragma unroll
    for (int m = 0; m < 4; ++m)
#pragma unroll
        for (int t = 0; t < 2; ++t) acc[m][t] = (f4x){0.f, 0.f, 0.f, 0.f};

#pragma unroll
    for (int s = 0; s < 4; ++s) {
#pragma unroll
        for (int m = 0; m < 4; ++m) {
            int row = 16 * m + li;
            int kb = (32 * s + 8 * g) * 2;
            int off = row * 256 + (kb ^ ((row & 7) << 4));
            h8 ah = *(const h8*)((const char*)xsh + off);
            h8 al = *(const h8*)((const char*)xsl + off);
#pragma unroll
            for (int t = 0; t < 2; ++t) {
                acc[m][t] = __builtin_amdgcn_mfma_f32_16x16x32_f16(ah, Bh[t][s], acc[m][t], 0, 0, 0);
                acc[m][t] = __builtin_amdgcn_mfma_f32_16x16x32_f16(al, Bh[t][s], acc[m][t], 0, 0, 0);
                acc[m][t] = __builtin_amdgcn_mfma_f32_16x16x32_f16(ah, Bl[t][s], acc[m][t], 0, 0, 0);
            }
        }
    }

    // Epilogue 1: attn dots from fp32 acc. C/D: col = li, row = 4*g + reg.
    float at_s0 = attf[c0 + li],       at_s1 = attf[c0 + 16 + li];
    float at_d0 = attf[128 + c0 + li], at_d1 = attf[128 + c0 + 16 + li];
#pragma unroll
    for (int m = 0; m < 4; ++m) {
        float s1v[4], s2v[4];
#pragma unroll
        for (int j = 0; j < 4; ++j) {
            s1v[j] = acc[m][0][j] * at_s0 + acc[m][1][j] * at_s1;
            s2v[j] = acc[m][0][j] * at_d0 + acc[m][1][j] * at_d1;
        }
#pragma unroll
        for (int j = 0; j < 4; ++j) {
#pragma unroll
            for (int msk = 1; msk < 16; msk <<= 1) {
                s1v[j] += __shfl_xor(s1v[j], msk);
                s2v[j] += __shfl_xor(s2v[j], msk);
            }
        }
        if (li == 0) {
#pragma unroll
            for (int j = 0; j < 4; ++j) {
                int gr = r0 + 16 * m + 4 * g + j;
                if (gr < N) {
                    asf[(size_t)gr * 4 + w] = s1v[j];
                    adf[(size_t)gr * 4 + w] = s2v[j];
                }
            }
        }
    }

    // Epilogue 2: h -> bf16 via LDS (reuse hi-plane) for coalesced store.
    __syncthreads();
#pragma unroll
    for (int m = 0; m < 4; ++m)
#pragma unroll
        for (int t = 0; t < 2; ++t)
#pragma unroll
            for (int j = 0; j < 4; ++j)
                xsh[(16 * m + 4 * g + j) * 128 + c0 + 16 * t + li] = f2b(acc[m][t][j]);
    __syncthreads();
#pragma unroll
    for (int it = 0; it < 4; ++it) {
        int u = it * 2048 + tid * 8;
        int r = u >> 7, k = u & 127;
        int gr = r0 + r;
        if (gr < N)
            *(uint4*)(hbf + (size_t)gr * 128 + k) = *(const uint4*)(xsh + u);
    }
}

// --- 2. fused demux + aggregate: one block per 64-node bucket ---------------
// Fast path (deg<=31): PAIRED gathers. Wave instruction k covers items
// {2k, 2k+1}: lanes 0-31 read item 2k's row, lanes 32-63 item 2k+1's row,
// dwordx2/lane = channels 4*(lane&31)..+3. Final shfl_xor(32) merges halves.
// psh layout: [head*PST + item]; item 0 = self-loop, item k = edge k-1.
template <int NB>  // batches of 16 items (8 instructions); NB in {1,2}
__device__ __forceinline__ void agg_node2(
    int n, int dl, int deg, int lane,
    const int lslot[64][SLOT], float* psh,
    const unsigned short* __restrict__ hbf,
    const float* __restrict__ asf, const float* __restrict__ adf,
    float a[4], float& invho) {
    int half = lane >> 5;        // which item of each pair this lane serves
    int cl = lane & 31;          // channel-group lane: channels 4cl..4cl+3
    int hd = cl >> 3;            // head for those channels
    // (1) issue asf/adf row loads (oldest in vmcnt queue)
    int sl = (lane == 0) ? n : ((lane <= deg) ? lslot[dl][lane - 1] : n);
    float4 av, adv;
    asm volatile("global_load_dwordx4 %0, %1, off"
                 : "=v"(av) : "v"((const void*)(asf + (size_t)sl * 4)));
    asm volatile("global_load_dwordx4 %0, %1, off"
                 : "=v"(adv) : "v"((const void*)(adf + (size_t)n * 4)));
    // (2) issue ALL h-row gathers: 2 items per instruction, dwordx2/lane
    u32x2 vv[NB * 8];
#pragma unroll
    for (int k = 0; k < NB * 8; ++k) {
        int it = 2 * k + half;
        int s = (it == 0) ? n : ((it <= deg) ? lslot[dl][it - 1] : n);
        asm volatile("global_load_dwordx2 %0, %1, off"
                     : "=v"(vv[k]) : "v"((const void*)(hbf + (size_t)s * 128 + 4 * cl)));
    }
    // (3) wait only for av/adv (2 oldest); h loads stay in flight
    asm volatile("s_waitcnt vmcnt(%0)" :: "n"(NB * 8));
    __builtin_amdgcn_sched_barrier(0);

    float p0 = 0.f, p1 = 0.f, p2 = 0.f, p3 = 0.f;
    if (lane <= deg) {
        float e0 = av.x + adv.x; e0 = fmaxf(e0, 0.2f * e0); p0 = __expf(e0);
        float e1 = av.y + adv.y; e1 = fmaxf(e1, 0.2f * e1); p1 = __expf(e1);
        float e2 = av.z + adv.z; e2 = fmaxf(e2, 0.2f * e2); p2 = __expf(e2);
        float e3 = av.w + adv.w; e3 = fmaxf(e3, 0.2f * e3); p3 = __expf(e3);
    }
    psh[0 * PST + lane] = p0; psh[1 * PST + lane] = p1;   // zeros beyond deg
    psh[2 * PST + lane] = p2; psh[3 * PST + lane] = p3;   //  -> padded q = 0
    __builtin_amdgcn_wave_barrier();
    asm volatile("s_waitcnt lgkmcnt(0)" ::: "memory");
    __builtin_amdgcn_wave_barrier();

    float ps0 = p0, ps1 = p1, ps2 = p2, ps3 = p3;
#pragma unroll
    for (int m = 1; m < 64; m <<= 1) {     // 64-lane butterfly denom
        ps0 += __shfl_xor(ps0, m);
        ps1 += __shfl_xor(ps1, m);
        ps2 += __shfl_xor(ps2, m);
        ps3 += __shfl_xor(ps3, m);
    }
    float den = hd == 0 ? ps0 : hd == 1 ? ps1 : hd == 2 ? ps2 : ps3;
    invho = 1.0f / (den + 1e-16f);

    // (4) consume with counted drains; q scalar LDS reads (8 bcast groups,
    //     conflict-free banks: it + 4*hd)
#pragma unroll
    for (int bi = 0; bi < NB; ++bi) {
        asm volatile("s_waitcnt vmcnt(%0)" :: "n"(8 * (NB - 1 - bi)));
        __builtin_amdgcn_sched_barrier(0);
#pragma unroll
        for (int k2 = 0; k2 < 8; ++k2) {
            int it = 2 * (bi * 8 + k2) + half;
            float q = psh[hd * PST + it];
            u32x2 v = vv[bi * 8 + k2];
            a[0] += q * b2f((unsigned short)v[0]);
            a[1] += q * b2f((unsigned short)(v[0] >> 16));
            a[2] += q * b2f((unsigned short)v[1]);
            a[3] += q * b2f((unsigned short)(v[1] >> 16));
        }
    }
}

__global__ __launch_bounds__(256) void k_bagg(
    const unsigned* __restrict__ bdat, const int* __restrict__ bcnt,
    const unsigned short* __restrict__ hbf,
    const float* __restrict__ asf, const float* __restrict__ adf,
    const int* __restrict__ idx32, const long long* __restrict__ idx64,
    const float* __restrict__ biasf, const int* __restrict__ flags,
    void* __restrict__ outv, int N, int E) {
    __shared__ int   lcnt[64];
    __shared__ int   lslot[64][SLOT];          // 16KB
    __shared__ float p_all[4][4 * PST];        // per-wave, stride-68 rows
    int b = blockIdx.x, tid = threadIdx.x;
    int wid = tid >> 6, lane = tid & 63, head = lane >> 4;

    if (tid < 64) lcnt[tid] = 0;
    __syncthreads();
    int mm = bcnt[(size_t)b * BCNS];
    int ovf = (mm > BCAP);
    if (mm > BCAP) mm = BCAP;
    for (int i = tid; i < mm; i += 256) {      // demux bucket -> LDS CSR
        unsigned e = bdat[(size_t)b * BCAP + i];
        int dl = (int)(e >> 26);
        int p = atomicAdd(&lcnt[dl], 1);
        if (p < SLOT) lslot[dl][p] = (int)(e & 0x03FFFFFFu);
    }
    __syncthreads();

    int cl = lane & 31;
    float b0 = biasf[2 * lane], b1 = biasf[2 * lane + 1];   // old-mapping paths
    float4 bq4 = *(const float4*)(biasf + 4 * cl);          // paired fast path
    float* psh = p_all[wid];
    int isbf = flags[1];
    int is64 = flags[0];

    for (int u = 0; u < 16; ++u) {             // 16 nodes per wave, no block sync
        int dl = wid * 16 + u;
        int n = (b << 6) + dl;
        if (n >= N) break;                     // wave-uniform
        int deg = lcnt[dl];
        bool fb = ovf || (deg > SLOT - 1);

        if (!fb && deg <= 31) {
            // ---- paired fast path ----
            float a4[4] = {0.f, 0.f, 0.f, 0.f};
            float invh = 0.f;
            int nb = (deg + 16) >> 4;          // ceil((deg+1)/16), wave-uniform
            if (nb == 1) agg_node2<1>(n, dl, deg, lane, lslot, psh, hbf, asf, adf, a4, invh);
            else         agg_node2<2>(n, dl, deg, lane, lslot, psh, hbf, asf, adf, a4, invh);
#pragma unroll
            for (int c = 0; c < 4; ++c) a4[c] += __shfl_xor(a4[c], 32);
            float o0 = a4[0] * invh + bq4.x, o1 = a4[1] * invh + bq4.y;
            float o2 = a4[2] * invh + bq4.z, o3 = a4[3] * invh + bq4.w;
            if (lane < 32) {
                if (isbf) {
                    u32x2 pk;
                    pk[0] = (unsigned)f2b(o0) | ((unsigned)f2b(o1) << 16);
                    pk[1] = (unsigned)f2b(o2) | ((unsigned)f2b(o3) << 16);
                    *(u32x2*)((unsigned*)outv + (size_t)n * 64 + cl * 2) = pk;
                } else {
                    float4 f4v; f4v.x = o0; f4v.y = o1; f4v.z = o2; f4v.w = o3;
                    *(float4*)((float*)outv + (size_t)n * 128 + cl * 4) = f4v;
                }
            }
        } else if (!fb) {
            // ---- generic path (32 <= deg <= 63): old mapping, plain C ----
            float a0 = 0.f, a1 = 0.f;
            float4 adv = *(const float4*)(adf + (size_t)n * 4);
            int sl = (lane == 0) ? n : ((lane <= deg) ? lslot[dl][lane - 1] : n);
            float4 av = *(const float4*)(asf + (size_t)sl * 4);
            float p0 = 0.f, p1 = 0.f, p2 = 0.f, p3 = 0.f;
            if (lane <= deg) {
                float e0 = av.x + adv.x; e0 = fmaxf(e0, 0.2f * e0); p0 = __expf(e0);
                float e1 = av.y + adv.y; e1 = fmaxf(e1, 0.2f * e1); p1 = __expf(e1);
                float e2 = av.z + adv.z; e2 = fmaxf(e2, 0.2f * e2); p2 = __expf(e2);
                float e3 = av.w + adv.w; e3 = fmaxf(e3, 0.2f * e3); p3 = __expf(e3);
            }
            psh[0 * PST + lane] = p0; psh[1 * PST + lane] = p1;
            psh[2 * PST + lane] = p2; psh[3 * PST + lane] = p3;
            __builtin_amdgcn_wave_barrier();
            asm volatile("s_waitcnt lgkmcnt(0)" ::: "memory");
            __builtin_amdgcn_wave_barrier();
            float ps0 = p0, ps1 = p1, ps2 = p2, ps3 = p3;
#pragma unroll
            for (int m = 1; m < 64; m <<= 1) {
                ps0 += __shfl_xor(ps0, m);
                ps1 += __shfl_xor(ps1, m);
                ps2 += __shfl_xor(ps2, m);
                ps3 += __shfl_xor(ps3, m);
            }
            float den = head == 0 ? ps0 : head == 1 ? ps1 : head == 2 ? ps2 : ps3;
            float invh = 1.0f / (den + 1e-16f);
            int nb = (deg + 8) >> 3;
            for (int bi = 0; bi < nb; ++bi) {
                unsigned vt[8];
#pragma unroll
                for (int k2 = 0; k2 < 8; ++k2) {
                    int it = bi * 8 + k2;
                    int s = (it == 0) ? n : ((it <= deg) ? lslot[dl][it - 1] : n);
                    vt[k2] = *(const unsigned int*)(hbf + (size_t)s * 128 + 2 * lane);
                }
#pragma unroll
                for (int k2 = 0; k2 < 8; ++k2) {
                    float q = psh[head * PST + bi * 8 + k2];
                    a0 += q * b2f((unsigned short)vt[k2]);
                    a1 += q * b2f((unsigned short)(vt[k2] >> 16));
                }
            }
            a0 = a0 * invh + b0;
            a1 = a1 * invh + b1;
            if (isbf) {
                unsigned int pk = (unsigned int)f2b(a0) | ((unsigned int)f2b(a1) << 16);
                ((unsigned int*)outv)[(size_t)n * 64 + lane] = pk;
            } else {
                float2 f2; f2.x = a0; f2.y = a1;
                *(float2*)((float*)outv + (size_t)n * 128 + 2 * lane) = f2;
            }
        } else {
            // ---- parachute: deg >= SLOT or bucket overflow. Full rescan ----
            float a0 = 0.f, a1 = 0.f;
            float4 adv = *(const float4*)(adf + (size_t)n * 4);
            float adh = head == 0 ? adv.x : head == 1 ? adv.y : head == 2 ? adv.z : adv.w;
            float den = 0.f;
            {   // self-loop
                float ev = asf[(size_t)n * 4 + head] + adh; ev = fmaxf(ev, 0.2f * ev);
                float p = __expf(ev);
                unsigned int v = *(const unsigned int*)(hbf + (size_t)n * 128 + 2 * lane);
                den += p;
                a0 += p * b2f((unsigned short)v);
                a1 += p * b2f((unsigned short)(v >> 16));
            }
            for (int e = 0; e < E; ++e) {
                int d = edge_at(idx32, idx64, is64, (long long)E + e);
                if (d == n) {
                    int s = edge_at(idx32, idx64, is64, e);
                    float ev = asf[(size_t)s * 4 + head] + adh; ev = fmaxf(ev, 0.2f * ev);
                    float p = __expf(ev);
                    unsigned int v = *(const unsigned int*)(hbf + (size_t)s * 128 + 2 * lane);
                    den += p;
                    a0 += p * b2f((unsigned short)v);
                    a1 += p * b2f((unsigned short)(v >> 16));
                }
            }
            float invh = 1.0f / (den + 1e-16f);
            a0 = a0 * invh + b0;
            a1 = a1 * invh + b1;
            if (isbf) {
                unsigned int pk = (unsigned int)f2b(a0) | ((unsigned int)f2b(a1) << 16);
                ((unsigned int*)outv)[(size_t)n * 64 + lane] = pk;
            } else {
                float2 f2; f2.x = a0; f2.y = a1;
                *(float2*)((float*)outv + (size_t)n * 128 + 2 * lane) = f2;
            }
        }
        __builtin_amdgcn_wave_barrier();
    }
}

// --- 2L. legacy aggregate (NBK > MAXB only): one wave per node --------------
__global__ __launch_bounds__(256) void k_aggregate(
    const unsigned short* __restrict__ hbf,
    const float* __restrict__ asf, const float* __restrict__ adf,
    const int* __restrict__ cnt, const int* __restrict__ esrc,
    const int* __restrict__ idx32, const long long* __restrict__ idx64,
    const float* __restrict__ biasf, const int* __restrict__ flags,
    void* __restrict__ outv, int N, int E) {
    __shared__ float p_sh_all[4][SLOT * 4];
    __shared__ int   s_sh_all[4][SLOT];
    int wid = threadIdx.x >> 6;
    int lane = threadIdx.x & 63;
    int n = blockIdx.x * 4 + wid;
    if (n >= N) n = N - 1;                     // tail waves redo a node (benign)
    float* p_sh = p_sh_all[wid];
    int*   s_sh = s_sh_all[wid];
    int head = lane >> 4;

    int deg = cnt[(size_t)n * CNTS];           // edges, excl. self-loop
    float4 adv = *(const float4*)(adf + (size_t)n * 4);
    bool fb = (deg > SLOT - 1);                // total deg+1 must fit in 64

    float p0 = 0.f, p1 = 0.f, p2 = 0.f, p3 = 0.f;
    if (!fb && lane <= deg) {                  // phase 1: one item per lane
        int s = (lane == 0) ? n : esrc[(size_t)n * SLOT + lane - 1];
        float4 av = *(const float4*)(asf + (size_t)s * 4);
        float e0 = av.x + adv.x; e0 = fmaxf(e0, 0.2f * e0); p0 = __expf(e0);
        float e1 = av.y + adv.y; e1 = fmaxf(e1, 0.2f * e1); p1 = __expf(e1);
        float e2 = av.z + adv.z; e2 = fmaxf(e2, 0.2f * e2); p2 = __expf(e2);
        float e3 = av.w + adv.w; e3 = fmaxf(e3, 0.2f * e3); p3 = __expf(e3);
        s_sh[lane] = s;
        p_sh[lane * 4 + 0] = p0; p_sh[lane * 4 + 1] = p1;
        p_sh[lane * 4 + 2] = p2; p_sh[lane * 4 + 3] = p3;
    }
    __syncthreads();

    float b0 = biasf[2 * lane], b1 = biasf[2 * lane + 1];
    float a0 = 0.f, a1 = 0.f, invh;

    if (!fb) {
        float ps0 = p0, ps1 = p1, ps2 = p2, ps3 = p3;
#pragma unroll
        for (int m = 1; m < 64; m <<= 1) {     // 64-lane butterfly
            ps0 += __shfl_xor(ps0, m);
            ps1 += __shfl_xor(ps1, m);
            ps2 += __shfl_xor(ps2, m);
            ps3 += __shfl_xor(ps3, m);
        }
        float den = head == 0 ? ps0 : head == 1 ? ps1 : head == 2 ? ps2 : ps3;
        invh = 1.0f / (den + 1e-16f);

        int tot = deg + 1;
        int i = 0;
        for (; i + 3 < tot; i += 4) {          // 4 row-gathers in flight
            int s0 = s_sh[i], s1 = s_sh[i + 1], s2 = s_sh[i + 2], s3 = s_sh[i + 3];
            float q0 = p_sh[i * 4 + head],       q1 = p_sh[(i + 1) * 4 + head];
            float q2 = p_sh[(i + 2) * 4 + head], q3 = p_sh[(i + 3) * 4 + head];
            unsigned int v0 = *(const unsigned int*)(hbf + (size_t)s0 * 128 + 2 * lane);
            unsigned int v1 = *(const unsigned int*)(hbf + (size_t)s1 * 128 + 2 * lane);
            unsigned int v2 = *(const unsigned int*)(hbf + (size_t)s2 * 128 + 2 * lane);
            unsigned int v3 = *(const unsigned int*)(hbf + (size_t)s3 * 128 + 2 * lane);
            a0 += q0 * b2f((unsigned short)v0) + q1 * b2f((unsigned short)v1)
                + q2 * b2f((unsigned short)v2) + q3 * b2f((unsigned short)v3);
            a1 += q0 * b2f((unsigned short)(v0 >> 16)) + q1 * b2f((unsigned short)(v1 >> 16))
                + q2 * b2f((unsigned short)(v2 >> 16)) + q3 * b2f((unsigned short)(v3 >> 16));
        }
        for (; i < tot; ++i) {
            int s0 = s_sh[i];
            float q0 = p_sh[i * 4 + head];
            unsigned int v0 = *(const unsigned int*)(hbf + (size_t)s0 * 128 + 2 * lane);
            a0 += q0 * b2f((unsigned short)v0);
            a1 += q0 * b2f((unsigned short)(v0 >> 16));
        }
    } else {
        int is64 = flags[0];
        float adh = head == 0 ? adv.x : head == 1 ? adv.y : head == 2 ? adv.z : adv.w;
        float den = 0.f;
        {   // self-loop
            float ev = asf[(size_t)n * 4 + head] + adh; ev = fmaxf(ev, 0.2f * ev);
            float p = __expf(ev);
            unsigned int v = *(const unsigned int*)(hbf + (size_t)n * 128 + 2 * lane);
            den += p;
            a0 += p * b2f((unsigned short)v);
            a1 += p * b2f((unsigned short)(v >> 16));
        }
        for (int e = 0; e < E; ++e) {
            int d = edge_at(idx32, idx64, is64, (long long)E + e);
            if (d == n) {
                int s = edge_at(idx32, idx64, is64, e);
                float ev = asf[(size_t)s * 4 + head] + adh; ev = fmaxf(ev, 0.2f * ev);
                float p = __expf(ev);
                unsigned int v = *(const unsigned int*)(hbf + (size_t)s * 128 + 2 * lane);
                den += p;
                a0 += p * b2f((unsigned short)v);
                a1 += p * b2f((unsigned short)(v >> 16));
            }
        }
        invh = 1.0f / (den + 1e-16f);
    }

    a0 = a0 * invh + b0;
    a1 = a1 * invh + b1;
    if (flags[1]) {
        unsigned int pk = (unsigned int)f2b(a0) | ((unsigned int)f2b(a1) << 16);
        ((unsigned int*)outv)[(size_t)n * 64 + lane] = pk;
    } else {
        float2 f2; f2.x = a0; f2.y = a1;
        *(float2*)((float*)outv + (size_t)n * 128 + 2 * lane) = f2;
    }
}

// ---------------------------------------------------------------------------
extern "C" void kernel_launch(void* const* d_in, const int* in_sizes, int n_in,
                              void* d_out, int out_size, void* d_ws, size_t ws_size,
                              hipStream_t stream) {
    const void*      xv    = d_in[0];
    const int*       idx32 = (const int*)d_in[1];
    const long long* idx64 = (const long long*)d_in[1];

    int N = in_sizes[0] / 128;
    int E = in_sizes[1] / 2;

    char* ws = (char*)d_ws;
    size_t o = 0;
    auto alloc = [&](size_t bytes) {
        size_t r = o; o += (bytes + 255) & ~(size_t)255; return r;
    };
    unsigned short* hbf = (unsigned short*)(ws + alloc((size_t)N * 128 * 2));
    _Float16* Wth = (_Float16*)(ws + alloc(16384 * 2));
    _Float16* Wtl = (_Float16*)(ws + alloc(16384 * 2));
    float* attf  = (float*)(ws + alloc(256 * 4));
    float* biasf = (float*)(ws + alloc(128 * 4));
    float* asf   = (float*)(ws + alloc((size_t)N * 4 * 4));
    float* adf   = (float*)(ws + alloc((size_t)N * 4 * 4));
    int* cnt     = (int*)(ws + alloc((size_t)N * CNTS * 4));
    int* flags   = (int*)(ws + alloc(256));
    int* esrc    = (int*)(ws + alloc((size_t)N * SLOT * 4));
    int NBK = (N + 63) >> 6;
    int* bcnt      = (int*)(ws + alloc((size_t)NBK * BCNS * 4));
    unsigned* bdat = (unsigned*)(ws + alloc((size_t)NBK * BCAP * 4));

    int Gg = (N + 63) / 64;                  // gemm tiles (64 rows each)
    int SB = (E + KCH - 1) / KCH;            // scatter chunks
    int NB = SB + Gg;

    k_detect<<<1, 256, 0, stream>>>(idx32, (const unsigned int*)xv, flags);
    k_prep<<<16, 256, 0, stream>>>(d_in[2], d_in[3], d_in[4], d_in[5], flags, Wth, Wtl, attf, biasf);
    if (NBK <= MAXB) {
        hipMemsetAsync(bcnt, 0, (size_t)NBK * BCNS * 4, stream);
        k_gemm_scatter<<<NB, 256, 0, stream>>>(xv, Wth, Wtl, attf, flags, hbf, asf, adf, N,
                                               idx32, idx64, bcnt, bdat, cnt, esrc, E, Gg, SB);
        k_bagg<<<NBK, 256, 0, stream>>>(bdat, bcnt, hbf, asf, adf, idx32, idx64,
                                        biasf, flags, d_out, N, E);
    } else {
        hipMemsetAsync(cnt, 0, (size_t)N * CNTS * 4, stream);
        k_gemm_scatter<<<NB, 256, 0, stream>>>(xv, Wth, Wtl, attf, flags, hbf, asf, adf, N,
                                               idx32, idx64, bcnt, bdat, cnt, esrc, E, Gg, SB);
        k_aggregate<<<(N + 3) / 4, 256, 0, stream>>>(hbf, asf, adf, cnt, esrc, idx32, idx64,
                                                     biasf, flags, d_out, N, E);
    }
}

// Round 9
// 252.247 us; speedup vs baseline: 1.0994x; 1.0069x over previous
//
#include <hip/hip_runtime.h>
#include <stdint.h>

// ---------------------------------------------------------------------------
// GAT layer, dtype-adaptive (probed: fp32 inputs, int32 edge_index, bf16 out).
//   prep:   flags probe (folded-in detect) + W^T hi/lo f16 + att/bias fp32
//           + bcnt zeroing. 3 dispatches total (was 5).
//   fused:  h = x@W via split-f16 MFMA (fp32-grade), attn dots in epilogue
//           [blocks SB..SB+Gg)]
//           bucketed scatter: 64-node buckets, PER-WAVE LDS histograms +
//           one device atomic per (block,bucket) run-claim (bcnt line-padded
//           64B/bucket), per-wave cursor sub-runs, KCH=8192 [blocks 0..SB)]
//   bagg:   fused demux+aggregate, TWO blocks per bucket (redundant demux,
//           each block aggregates 32 of the 64 nodes, 8/wave) -> 3126 blocks,
//           ~2x occupancy to hide the per-node gather latency chain.
//           PAIRED gathers: lanes 0-31 = even item's row, lanes 32-63 = odd,
//           dwordx2/lane; asm-pinned schedule, counted vmcnt drains;
//           psh stride 68 (bank-conflict-free).
//   legacy (N > 131072): per-edge scatter into cnt/esrc + old k_aggregate.
// ---------------------------------------------------------------------------

#define SLOT 64
#define CNTS 16    // counter stride in ints (legacy path)
#define BCNS 16    // bcnt stride in ints = one 64B line per bucket
#define BCAP 1536  // bucket capacity (entries); avg fill 1024, ~16 sigma slack
#define MAXB 2048  // max buckets (N <= 131072); 4 per-wave hists = 32KB LDS
#define KCH  8192  // edges per scatter chunk
#define PST  68    // psh stride in floats (272B -> banks rotate 4 per head)

typedef __attribute__((ext_vector_type(8))) _Float16 h8;
typedef __attribute__((ext_vector_type(4))) float    f4x;
typedef __attribute__((ext_vector_type(2))) unsigned u32x2;

__device__ __forceinline__ float b2f(unsigned short u) {
    union { unsigned int i; float f; } v; v.i = ((unsigned int)u) << 16; return v.f;
}
__device__ __forceinline__ unsigned short f2b(float f) {
    union { float f; unsigned int i; } v; v.f = f;
    unsigned int i = v.i;
    unsigned int r = (i + 0x7FFFu + ((i >> 16) & 1u)) >> 16;  // RNE
    return (unsigned short)r;
}
__device__ __forceinline__ unsigned short f2h(float f) {
    union { _Float16 h; unsigned short u; } v; v.h = (_Float16)f; return v.u;
}
__device__ __forceinline__ float h2f(unsigned short u) {
    union { _Float16 h; unsigned short u; } v; v.u = u; return (float)v.h;
}

__device__ __forceinline__ int edge_at(const int* idx32, const long long* idx64,
                                       int is64, long long pos) {
    return is64 ? (int)idx64[pos] : idx32[pos];
}

// --- 0. prep: probes + W^T hi/lo f16 + att/bias fp32 + bcnt zero ------------
__global__ void k_prep(const void* __restrict__ Wv, const void* __restrict__ asv,
                       const void* __restrict__ adv, const void* __restrict__ bv,
                       const int* __restrict__ eidx, const unsigned int* __restrict__ xw,
                       int* __restrict__ flags,
                       _Float16* __restrict__ Wth, _Float16* __restrict__ Wtl,
                       float* __restrict__ attf /*256*/, float* __restrict__ biasf /*128*/,
                       int* __restrict__ bcnt, int nbcnt /*ints to zero*/) {
    __shared__ int nz, bf;
    int tid = threadIdx.x;
    if (tid == 0) { nz = 0; bf = 0; }
    __syncthreads();
    int hits = 0;
    for (int i = tid; i < 4096; i += 256) {       // every block: bf16 probe
        unsigned int e = (xw[i] >> 7) & 0xFFu;
        if (e >= 0x60u && e < 0xA0u) ++hits;
    }
    atomicAdd(&bf, hits);
    if (blockIdx.x == 0) {                        // block 0: int64 probe
        int bad = 0;
        for (int i = tid; i < 1024; i += 256)
            if (eidx[2 * i + 1] != 0) bad = 1;
        if (bad) atomicOr(&nz, 1);
    }
    __syncthreads();
    int isbf = (bf > 3072) ? 1 : 0;
    if (blockIdx.x == 0 && tid == 0) {
        flags[0] = (nz == 0) ? 1 : 0;   // 1 => int64 edge_index
        flags[1] = isbf;                // 1 => bf16 float tensors
    }
    for (int i = blockIdx.x * 256 + tid; i < nbcnt; i += gridDim.x * 256)
        bcnt[i] = 0;
    int gtid = blockIdx.x * 256 + tid;
    for (int i = gtid; i < 16384; i += gridDim.x * 256) {
        int col = i >> 7, k = i & 127;            // Wt[col][k] = W[k][col]
        float w = isbf ? b2f(((const unsigned short*)Wv)[k * 128 + col])
                       : ((const float*)Wv)[k * 128 + col];
        unsigned short hi = f2h(w);
        unsigned short lo = f2h(w - h2f(hi));
        ((unsigned short*)Wth)[i] = hi;
        ((unsigned short*)Wtl)[i] = lo;
    }
    if (blockIdx.x == 0) {
        for (int i = tid; i < 128; i += 256) {
            attf[i]       = isbf ? b2f(((const unsigned short*)asv)[i]) : ((const float*)asv)[i];
            attf[128 + i] = isbf ? b2f(((const unsigned short*)adv)[i]) : ((const float*)adv)[i];
            biasf[i]      = isbf ? b2f(((const unsigned short*)bv)[i]) : ((const float*)bv)[i];
        }
    }
}

// --- 1. fused MFMA GEMM (blocks >= SB) + bucketed scatter (blocks < SB) -----
__global__ __launch_bounds__(256) void k_gemm_scatter(
    const void* __restrict__ xv,
    const _Float16* __restrict__ Wth, const _Float16* __restrict__ Wtl,
    const float* __restrict__ attf, const int* __restrict__ flags,
    unsigned short* __restrict__ hbf, float* __restrict__ asf,
    float* __restrict__ adf, int N,
    const int* __restrict__ idx32, const long long* __restrict__ idx64,
    int* __restrict__ bcnt, unsigned* __restrict__ bdat,
    int* __restrict__ cnt, int* __restrict__ esrc,
    int E, int Gg, int SB) {
    __shared__ unsigned short xsh[64 * 128];   // x hi-plane / scatter hists 0,1
    __shared__ unsigned short xsl[64 * 128];   // x lo-plane / scatter hists 2,3
    int tid = threadIdx.x;
    int bid = blockIdx.x;

    if (bid < SB) {                            // ---- bucketed scatter ----
        int is64 = flags[0];
        int NBK = (N + 63) >> 6;
        long long e0 = (long long)bid * KCH;
        long long e1 = e0 + KCH; if (e1 > E) e1 = E;
        if (e0 >= E) return;

        if (NBK <= MAXB) {
            int wid = tid >> 6;
            int* h0 = (int*)xsh; int* h1 = h0 + MAXB;
            int* h2 = (int*)xsl; int* h3 = h2 + MAXB;
            int* hw = (wid == 0) ? h0 : (wid == 1) ? h1 : (wid == 2) ? h2 : h3;
            for (int i = tid; i < NBK; i += 256) { h0[i] = 0; h1[i] = 0; h2[i] = 0; h3[i] = 0; }
            __syncthreads();
            // pass 1: per-wave chunk histograms (intra-wave RMW only)
            for (long long e = e0 + tid; e < e1; e += 256) {
                int d = is64 ? (int)idx64[(long long)E + e] : idx32[E + e];
                atomicAdd(&hw[d >> 6], 1);
            }
            __syncthreads();
            // claim: ONE device atomic per non-empty bucket (64B-padded line);
            // per-wave sub-runs
            for (int b = tid; b < NBK; b += 256) {
                int c0 = h0[b], c1 = h1[b], c2 = h2[b], c3 = h3[b];
                int t = c0 + c1 + c2 + c3;
                int base = (t > 0) ? atomicAdd(&bcnt[(size_t)b * BCNS], t) : 0;
                h0[b] = base;
                h1[b] = base + c0;
                h2[b] = base + c0 + c1;
                h3[b] = base + c0 + c1 + c2;
            }
            __syncthreads();
            // pass 2: place entries at per-wave LDS cursors
            for (long long e = e0 + tid; e < e1; e += 256) {
                int d, s;
                if (is64) {
                    d = (int)idx64[(long long)E + e]; s = (int)idx64[e];
                } else {
                    d = idx32[E + e]; s = idx32[e];
                }
                int b = d >> 6;
                int p = atomicAdd(&hw[b], 1);
                if (p < BCAP)
                    bdat[(size_t)b * BCAP + p] = (unsigned)s | ((unsigned)(d & 63) << 26);
            }
        } else {
            // legacy per-edge path (host memsets cnt, uses old k_aggregate)
            for (long long e = e0 + tid; e < e1; e += 256) {
                int d = edge_at(idx32, idx64, is64, (long long)E + e);
                int s = edge_at(idx32, idx64, is64, e);
                int p = atomicAdd(&cnt[(size_t)d * CNTS], 1);
                if (p < SLOT) esrc[(size_t)d * SLOT + p] = s;
            }
        }
        return;
    }

    // ---- MFMA GEMM (unchanged) ----
    int rb = bid - SB;
    if (rb >= Gg) return;
    int r0 = rb * 64;
    int isbf = flags[1];
    int w = tid >> 6;            // wave id = head id (owns cols [32w, 32w+32))
    int lane = tid & 63;
    int li = lane & 15;          // fragment row/col index
    int g  = lane >> 4;          // k-group
    int c0 = w * 32;

    h8 Bh[2][4], Bl[2][4];
#pragma unroll
    for (int t = 0; t < 2; ++t)
#pragma unroll
        for (int s = 0; s < 4; ++s) {
            size_t o = (size_t)(c0 + 16 * t + li) * 128 + 32 * s + 8 * g;
            Bh[t][s] = *(const h8*)(Wth + o);
            Bl[t][s] = *(const h8*)(Wtl + o);
        }

#pragma unroll
    for (int it = 0; it < 4; ++it) {
        int idx = it * 2048 + tid * 8;         // 8 elements per thread per iter
        int r = idx >> 7, k = idx & 127;
        int gr = r0 + r; if (gr >= N) gr = N - 1;
        float v[8];
        if (isbf) {
            uint4 raw = *(const uint4*)((const unsigned short*)xv + (size_t)gr * 128 + k);
            v[0] = b2f((unsigned short)(raw.x & 0xFFFFu)); v[1] = b2f((unsigned short)(raw.x >> 16));
            v[2] = b2f((unsigned short)(raw.y & 0xFFFFu)); v[3] = b2f((unsigned short)(raw.y >> 16));
            v[4] = b2f((unsigned short)(raw.z & 0xFFFFu)); v[5] = b2f((unsigned short)(raw.z >> 16));
            v[6] = b2f((unsigned short)(raw.w & 0xFFFFu)); v[7] = b2f((unsigned short)(raw.w >> 16));
        } else {
            const float* xf = (const float*)xv;
            float4 a = *(const float4*)(xf + (size_t)gr * 128 + k);
            float4 b = *(const float4*)(xf + (size_t)gr * 128 + k + 4);
            v[0] = a.x; v[1] = a.y; v[2] = a.z; v[3] = a.w;
            v[4] = b.x; v[5] = b.y; v[6] = b.z; v[7] = b.w;
        }
        uint4 PH, PL;
        unsigned int ph[4], pl[4];
#pragma unroll
        for (int jj = 0; jj < 4; ++jj) {
            unsigned short h0 = f2h(v[2 * jj]), h1 = f2h(v[2 * jj + 1]);
            unsigned short l0 = f2h(v[2 * jj] - h2f(h0));
            unsigned short l1 = f2h(v[2 * jj + 1] - h2f(h1));
            ph[jj] = (unsigned int)h0 | ((unsigned int)h1 << 16);
            pl[jj] = (unsigned int)l0 | ((unsigned int)l1 << 16);
        }
        PH.x = ph[0]; PH.y = ph[1]; PH.z = ph[2]; PH.w = ph[3];
        PL.x = pl[0]; PL.y = pl[1]; PL.z = pl[2]; PL.w = pl[3];
        int off = r * 256 + ((2 * k) ^ ((r & 7) << 4));   // 16B-slot XOR swizzle
        *(uint4*)((char*)xsh + off) = PH;
        *(uint4*)((char*)xsl + off) = PL;
    }
    __syncthreads();

    f4x acc[4][2];
#pragma unroll
    for (int m = 0; m < 4; ++m)
#pragma unroll
        for (int t = 0; t < 2; ++t) acc[m][t] = (f4x){0.f, 0.f, 0.f, 0.f};

#pragma unroll
    for (int s = 0; s < 4; ++s) {
#pragma unroll
        for (int m = 0; m < 4; ++m) {
            int row = 16 * m + li;
            int kb = (32 * s + 8 * g) * 2;
            int off = row * 256 + (kb ^ ((row & 7) << 4));
            h8 ah = *(const h8*)((const char*)xsh + off);
            h8 al = *(const h8*)((const char*)xsl + off);
#pragma unroll
            for (int t = 0; t < 2; ++t) {
                acc[m][t] = __builtin_amdgcn_mfma_f32_16x16x32_f16(ah, Bh[t][s], acc[m][t], 0, 0, 0);
                acc[m][t] = __builtin_amdgcn_mfma_f32_16x16x32_f16(al, Bh[t][s], acc[m][t], 0, 0, 0);
                acc[m][t] = __builtin_amdgcn_mfma_f32_16x16x32_f16(ah, Bl[t][s], acc[m][t], 0, 0, 0);
            }
        }
    }

    // Epilogue 1: attn dots from fp32 acc. C/D: col = li, row = 4*g + reg.
    float at_s0 = attf[c0 + li],       at_s1 = attf[c0 + 16 + li];
    float at_d0 = attf[128 + c0 + li], at_d1 = attf[128 + c0 + 16 + li];
#pragma unroll
    for (int m = 0; m < 4; ++m) {
        float s1v[4], s2v[4];
#pragma unroll
        for (int j = 0; j < 4; ++j) {
            s1v[j] = acc[m][0][j] * at_s0 + acc[m][1][j] * at_s1;
            s2v[j] = acc[m][0][j] * at_d0 + acc[m][1][j] * at_d1;
        }
#pragma unroll
        for (int j = 0; j < 4; ++j) {
#pragma unroll
            for (int msk = 1; msk < 16; msk <<= 1) {
                s1v[j] += __shfl_xor(s1v[j], msk);
                s2v[j] += __shfl_xor(s2v[j], msk);
            }
        }
        if (li == 0) {
#pragma unroll
            for (int j = 0; j < 4; ++j) {
                int gr = r0 + 16 * m + 4 * g + j;
                if (gr < N) {
                    asf[(size_t)gr * 4 + w] = s1v[j];
                    adf[(size_t)gr * 4 + w] = s2v[j];
                }
            }
        }
    }

    // Epilogue 2: h -> bf16 via LDS (reuse hi-plane) for coalesced store.
    __syncthreads();
#pragma unroll
    for (int m = 0; m < 4; ++m)
#pragma unroll
        for (int t = 0; t < 2; ++t)
#pragma unroll
            for (int j = 0; j < 4; ++j)
                xsh[(16 * m + 4 * g + j) * 128 + c0 + 16 * t + li] = f2b(acc[m][t][j]);
    __syncthreads();
#pragma unroll
    for (int it = 0; it < 4; ++it) {
        int u = it * 2048 + tid * 8;
        int r = u >> 7, k = u & 127;
        int gr = r0 + r;
        if (gr < N)
            *(uint4*)(hbf + (size_t)gr * 128 + k) = *(const uint4*)(xsh + u);
    }
}

// --- 2. fused demux + aggregate: TWO blocks per 64-node bucket --------------
// Fast path (deg<=31): PAIRED gathers. Wave instruction k covers items
// {2k, 2k+1}: lanes 0-31 read item 2k's row, lanes 32-63 item 2k+1's row,
// dwordx2/lane = channels 4*(lane&31)..+3. Final shfl_xor(32) merges halves.
// psh layout: [head*PST + item]; item 0 = self-loop, item k = edge k-1.
template <int NB>  // batches of 16 items (8 instructions); NB in {1,2}
__device__ __forceinline__ void agg_node2(
    int n, int dl, int deg, int lane,
    const int lslot[64][SLOT], float* psh,
    const unsigned short* __restrict__ hbf,
    const float* __restrict__ asf, const float* __restrict__ adf,
    float a[4], float& invho) {
    int half = lane >> 5;        // which item of each pair this lane serves
    int cl = lane & 31;          // channel-group lane: channels 4cl..4cl+3
    int hd = cl >> 3;            // head for those channels
    // (1) issue asf/adf row loads (oldest in vmcnt queue)
    int sl = (lane == 0) ? n : ((lane <= deg) ? lslot[dl][lane - 1] : n);
    float4 av, adv;
    asm volatile("global_load_dwordx4 %0, %1, off"
                 : "=v"(av) : "v"((const void*)(asf + (size_t)sl * 4)));
    asm volatile("global_load_dwordx4 %0, %1, off"
                 : "=v"(adv) : "v"((const void*)(adf + (size_t)n * 4)));
    // (2) issue ALL h-row gathers: 2 items per instruction, dwordx2/lane
    u32x2 vv[NB * 8];
#pragma unroll
    for (int k = 0; k < NB * 8; ++k) {
        int it = 2 * k + half;
        int s = (it == 0) ? n : ((it <= deg) ? lslot[dl][it - 1] : n);
        asm volatile("global_load_dwordx2 %0, %1, off"
                     : "=v"(vv[k]) : "v"((const void*)(hbf + (size_t)s * 128 + 4 * cl)));
    }
    // (3) wait only for av/adv (2 oldest); h loads stay in flight
    asm volatile("s_waitcnt vmcnt(%0)" :: "n"(NB * 8));
    __builtin_amdgcn_sched_barrier(0);

    float p0 = 0.f, p1 = 0.f, p2 = 0.f, p3 = 0.f;
    if (lane <= deg) {
        float e0 = av.x + adv.x; e0 = fmaxf(e0, 0.2f * e0); p0 = __expf(e0);
        float e1 = av.y + adv.y; e1 = fmaxf(e1, 0.2f * e1); p1 = __expf(e1);
        float e2 = av.z + adv.z; e2 = fmaxf(e2, 0.2f * e2); p2 = __expf(e2);
        float e3 = av.w + adv.w; e3 = fmaxf(e3, 0.2f * e3); p3 = __expf(e3);
    }
    psh[0 * PST + lane] = p0; psh[1 * PST + lane] = p1;   // zeros beyond deg
    psh[2 * PST + lane] = p2; psh[3 * PST + lane] = p3;   //  -> padded q = 0
    __builtin_amdgcn_wave_barrier();
    asm volatile("s_waitcnt lgkmcnt(0)" ::: "memory");
    __builtin_amdgcn_wave_barrier();

    float ps0 = p0, ps1 = p1, ps2 = p2, ps3 = p3;
#pragma unroll
    for (int m = 1; m < 64; m <<= 1) {     // 64-lane butterfly denom
        ps0 += __shfl_xor(ps0, m);
        ps1 += __shfl_xor(ps1, m);
        ps2 += __shfl_xor(ps2, m);
        ps3 += __shfl_xor(ps3, m);
    }
    float den = hd == 0 ? ps0 : hd == 1 ? ps1 : hd == 2 ? ps2 : ps3;
    invho = 1.0f / (den + 1e-16f);

    // (4) consume with counted drains; q scalar LDS reads (8 bcast groups)
#pragma unroll
    for (int bi = 0; bi < NB; ++bi) {
        asm volatile("s_waitcnt vmcnt(%0)" :: "n"(8 * (NB - 1 - bi)));
        __builtin_amdgcn_sched_barrier(0);
#pragma unroll
        for (int k2 = 0; k2 < 8; ++k2) {
            int it = 2 * (bi * 8 + k2) + half;
            float q = psh[hd * PST + it];
            u32x2 v = vv[bi * 8 + k2];
            a[0] += q * b2f((unsigned short)v[0]);
            a[1] += q * b2f((unsigned short)(v[0] >> 16));
            a[2] += q * b2f((unsigned short)v[1]);
            a[3] += q * b2f((unsigned short)(v[1] >> 16));
        }
    }
}

__global__ __launch_bounds__(256) void k_bagg(
    const unsigned* __restrict__ bdat, const int* __restrict__ bcnt,
    const unsigned short* __restrict__ hbf,
    const float* __restrict__ asf, const float* __restrict__ adf,
    const int* __restrict__ idx32, const long long* __restrict__ idx64,
    const float* __restrict__ biasf, const int* __restrict__ flags,
    void* __restrict__ outv, int N, int E) {
    __shared__ int   lcnt[64];
    __shared__ int   lslot[64][SLOT];          // 16KB
    __shared__ float p_all[4][4 * PST];        // per-wave, stride-68 rows
    int b = blockIdx.x >> 1;                   // bucket
    int bh = blockIdx.x & 1;                   // which 32-node half we own
    int tid = threadIdx.x;
    int wid = tid >> 6, lane = tid & 63, head = lane >> 4;

    if (tid < 64) lcnt[tid] = 0;
    __syncthreads();
    int mm = bcnt[(size_t)b * BCNS];
    int ovf = (mm > BCAP);
    if (mm > BCAP) mm = BCAP;
    for (int i = tid; i < mm; i += 256) {      // demux bucket -> LDS CSR
        unsigned e = bdat[(size_t)b * BCAP + i];
        int dl = (int)(e >> 26);
        int p = atomicAdd(&lcnt[dl], 1);
        if (p < SLOT) lslot[dl][p] = (int)(e & 0x03FFFFFFu);
    }
    __syncthreads();

    int cl = lane & 31;
    float b0 = biasf[2 * lane], b1 = biasf[2 * lane + 1];   // old-mapping paths
    float4 bq4 = *(const float4*)(biasf + 4 * cl);          // paired fast path
    float* psh = p_all[wid];
    int isbf = flags[1];
    int is64 = flags[0];

    for (int u = 0; u < 8; ++u) {              // 8 nodes per wave (half bucket)
        int dl = bh * 32 + wid * 8 + u;
        int n = (b << 6) + dl;
        if (n >= N) break;                     // wave-uniform
        int deg = lcnt[dl];
        bool fb = ovf || (deg > SLOT - 1);

        if (!fb && deg <= 31) {
            // ---- paired fast path ----
            float a4[4] = {0.f, 0.f, 0.f, 0.f};
            float invh = 0.f;
            int nb = (deg + 16) >> 4;          // ceil((deg+1)/16), wave-uniform
            if (nb == 1) agg_node2<1>(n, dl, deg, lane, lslot, psh, hbf, asf, adf, a4, invh);
            else         agg_node2<2>(n, dl, deg, lane, lslot, psh, hbf, asf, adf, a4, invh);
#pragma unroll
            for (int c = 0; c < 4; ++c) a4[c] += __shfl_xor(a4[c], 32);
            float o0 = a4[0] * invh + bq4.x, o1 = a4[1] * invh + bq4.y;
            float o2 = a4[2] * invh + bq4.z, o3 = a4[3] * invh + bq4.w;
            if (lane < 32) {
                if (isbf) {
                    u32x2 pk;
                    pk[0] = (unsigned)f2b(o0) | ((unsigned)f2b(o1) << 16);
                    pk[1] = (unsigned)f2b(o2) | ((unsigned)f2b(o3) << 16);
                    *(u32x2*)((unsigned*)outv + (size_t)n * 64 + cl * 2) = pk;
                } else {
                    float4 f4v; f4v.x = o0; f4v.y = o1; f4v.z = o2; f4v.w = o3;
                    *(float4*)((float*)outv + (size_t)n * 128 + cl * 4) = f4v;
                }
            }
        } else if (!fb) {
            // ---- generic path (32 <= deg <= 63): old mapping, plain C ----
            float a0 = 0.f, a1 = 0.f;
            float4 adv = *(const float4*)(adf + (size_t)n * 4);
            int sl = (lane == 0) ? n : ((lane <= deg) ? lslot[dl][lane - 1] : n);
            float4 av = *(const float4*)(asf + (size_t)sl * 4);
            float p0 = 0.f, p1 = 0.f, p2 = 0.f, p3 = 0.f;
            if (lane <= deg) {
                float e0 = av.x + adv.x; e0 = fmaxf(e0, 0.2f * e0); p0 = __expf(e0);
                float e1 = av.y + adv.y; e1 = fmaxf(e1, 0.2f * e1); p1 = __expf(e1);
                float e2 = av.z + adv.z; e2 = fmaxf(e2, 0.2f * e2); p2 = __expf(e2);
                float e3 = av.w + adv.w; e3 = fmaxf(e3, 0.2f * e3); p3 = __expf(e3);
            }
            psh[0 * PST + lane] = p0; psh[1 * PST + lane] = p1;
            psh[2 * PST + lane] = p2; psh[3 * PST + lane] = p3;
            __builtin_amdgcn_wave_barrier();
            asm volatile("s_waitcnt lgkmcnt(0)" ::: "memory");
            __builtin_amdgcn_wave_barrier();
            float ps0 = p0, ps1 = p1, ps2 = p2, ps3 = p3;
#pragma unroll
            for (int m = 1; m < 64; m <<= 1) {
                ps0 += __shfl_xor(ps0, m);
                ps1 += __shfl_xor(ps1, m);
                ps2 += __shfl_xor(ps2, m);
                ps3 += __shfl_xor(ps3, m);
            }
            float den = head == 0 ? ps0 : head == 1 ? ps1 : head == 2 ? ps2 : ps3;
            float invh = 1.0f / (den + 1e-16f);
            int nb = (deg + 8) >> 3;
            for (int bi = 0; bi < nb; ++bi) {
                unsigned vt[8];
#pragma unroll
                for (int k2 = 0; k2 < 8; ++k2) {
                    int it = bi * 8 + k2;
                    int s = (it == 0) ? n : ((it <= deg) ? lslot[dl][it - 1] : n);
                    vt[k2] = *(const unsigned int*)(hbf + (size_t)s * 128 + 2 * lane);
                }
#pragma unroll
                for (int k2 = 0; k2 < 8; ++k2) {
                    float q = psh[head * PST + bi * 8 + k2];
                    a0 += q * b2f((unsigned short)vt[k2]);
                    a1 += q * b2f((unsigned short)(vt[k2] >> 16));
                }
            }
            a0 = a0 * invh + b0;
            a1 = a1 * invh + b1;
            if (isbf) {
                unsigned int pk = (unsigned int)f2b(a0) | ((unsigned int)f2b(a1) << 16);
                ((unsigned int*)outv)[(size_t)n * 64 + lane] = pk;
            } else {
                float2 f2; f2.x = a0; f2.y = a1;
                *(float2*)((float*)outv + (size_t)n * 128 + 2 * lane) = f2;
            }
        } else {
            // ---- parachute: deg >= SLOT or bucket overflow. Full rescan ----
            float a0 = 0.f, a1 = 0.f;
            float4 adv = *(const float4*)(adf + (size_t)n * 4);
            float adh = head == 0 ? adv.x : head == 1 ? adv.y : head == 2 ? adv.z : adv.w;
            float den = 0.f;
            {   // self-loop
                float ev = asf[(size_t)n * 4 + head] + adh; ev = fmaxf(ev, 0.2f * ev);
                float p = __expf(ev);
                unsigned int v = *(const unsigned int*)(hbf + (size_t)n * 128 + 2 * lane);
                den += p;
                a0 += p * b2f((unsigned short)v);
                a1 += p * b2f((unsigned short)(v >> 16));
            }
            for (int e = 0; e < E; ++e) {
                int d = edge_at(idx32, idx64, is64, (long long)E + e);
                if (d == n) {
                    int s = edge_at(idx32, idx64, is64, e);
                    float ev = asf[(size_t)s * 4 + head] + adh; ev = fmaxf(ev, 0.2f * ev);
                    float p = __expf(ev);
                    unsigned int v = *(const unsigned int*)(hbf + (size_t)s * 128 + 2 * lane);
                    den += p;
                    a0 += p * b2f((unsigned short)v);
                    a1 += p * b2f((unsigned short)(v >> 16));
                }
            }
            float invh = 1.0f / (den + 1e-16f);
            a0 = a0 * invh + b0;
            a1 = a1 * invh + b1;
            if (isbf) {
                unsigned int pk = (unsigned int)f2b(a0) | ((unsigned int)f2b(a1) << 16);
                ((unsigned int*)outv)[(size_t)n * 64 + lane] = pk;
            } else {
                float2 f2; f2.x = a0; f2.y = a1;
                *(float2*)((float*)outv + (size_t)n * 128 + 2 * lane) = f2;
            }
        }
        __builtin_amdgcn_wave_barrier();
    }
}

// --- 2L. legacy aggregate (NBK > MAXB only): one wave per node --------------
__global__ __launch_bounds__(256) void k_aggregate(
    const unsigned short* __restrict__ hbf,
    const float* __restrict__ asf, const float* __restrict__ adf,
    const int* __restrict__ cnt, const int* __restrict__ esrc,
    const int* __restrict__ idx32, const long long* __restrict__ idx64,
    const float* __restrict__ biasf, const int* __restrict__ flags,
    void* __restrict__ outv, int N, int E) {
    __shared__ float p_sh_all[4][SLOT * 4];
    __shared__ int   s_sh_all[4][SLOT];
    int wid = threadIdx.x >> 6;
    int lane = threadIdx.x & 63;
    int n = blockIdx.x * 4 + wid;
    if (n >= N) n = N - 1;                     // tail waves redo a node (benign)
    float* p_sh = p_sh_all[wid];
    int*   s_sh = s_sh_all[wid];
    int head = lane >> 4;

    int deg = cnt[(size_t)n * CNTS];           // edges, excl. self-loop
    float4 adv = *(const float4*)(adf + (size_t)n * 4);
    bool fb = (deg > SLOT - 1);                // total deg+1 must fit in 64

    float p0 = 0.f, p1 = 0.f, p2 = 0.f, p3 = 0.f;
    if (!fb && lane <= deg) {                  // phase 1: one item per lane
        int s = (lane == 0) ? n : esrc[(size_t)n * SLOT + lane - 1];
        float4 av = *(const float4*)(asf + (size_t)s * 4);
        float e0 = av.x + adv.x; e0 = fmaxf(e0, 0.2f * e0); p0 = __expf(e0);
        float e1 = av.y + adv.y; e1 = fmaxf(e1, 0.2f * e1); p1 = __expf(e1);
        float e2 = av.z + adv.z; e2 = fmaxf(e2, 0.2f * e2); p2 = __expf(e2);
        float e3 = av.w + adv.w; e3 = fmaxf(e3, 0.2f * e3); p3 = __expf(e3);
        s_sh[lane] = s;
        p_sh[lane * 4 + 0] = p0; p_sh[lane * 4 + 1] = p1;
        p_sh[lane * 4 + 2] = p2; p_sh[lane * 4 + 3] = p3;
    }
    __syncthreads();

    float b0 = biasf[2 * lane], b1 = biasf[2 * lane + 1];
    float a0 = 0.f, a1 = 0.f, invh;

    if (!fb) {
        float ps0 = p0, ps1 = p1, ps2 = p2, ps3 = p3;
#pragma unroll
        for (int m = 1; m < 64; m <<= 1) {     // 64-lane butterfly
            ps0 += __shfl_xor(ps0, m);
            ps1 += __shfl_xor(ps1, m);
            ps2 += __shfl_xor(ps2, m);
            ps3 += __shfl_xor(ps3, m);
        }
        float den = head == 0 ? ps0 : head == 1 ? ps1 : head == 2 ? ps2 : ps3;
        invh = 1.0f / (den + 1e-16f);

        int tot = deg + 1;
        int i = 0;
        for (; i + 3 < tot; i += 4) {          // 4 row-gathers in flight
            int s0 = s_sh[i], s1 = s_sh[i + 1], s2 = s_sh[i + 2], s3 = s_sh[i + 3];
            float q0 = p_sh[i * 4 + head],       q1 = p_sh[(i + 1) * 4 + head];
            float q2 = p_sh[(i + 2) * 4 + head], q3 = p_sh[(i + 3) * 4 + head];
            unsigned int v0 = *(const unsigned int*)(hbf + (size_t)s0 * 128 + 2 * lane);
            unsigned int v1 = *(const unsigned int*)(hbf + (size_t)s1 * 128 + 2 * lane);
            unsigned int v2 = *(const unsigned int*)(hbf + (size_t)s2 * 128 + 2 * lane);
            unsigned int v3 = *(const unsigned int*)(hbf + (size_t)s3 * 128 + 2 * lane);
            a0 += q0 * b2f((unsigned short)v0) + q1 * b2f((unsigned short)v1)
                + q2 * b2f((unsigned short)v2) + q3 * b2f((unsigned short)v3);
            a1 += q0 * b2f((unsigned short)(v0 >> 16)) + q1 * b2f((unsigned short)(v1 >> 16))
                + q2 * b2f((unsigned short)(v2 >> 16)) + q3 * b2f((unsigned short)(v3 >> 16));
        }
        for (; i < tot; ++i) {
            int s0 = s_sh[i];
            float q0 = p_sh[i * 4 + head];
            unsigned int v0 = *(const unsigned int*)(hbf + (size_t)s0 * 128 + 2 * lane);
            a0 += q0 * b2f((unsigned short)v0);
            a1 += q0 * b2f((unsigned short)(v0 >> 16));
        }
    } else {
        int is64 = flags[0];
        float adh = head == 0 ? adv.x : head == 1 ? adv.y : head == 2 ? adv.z : adv.w;
        float den = 0.f;
        {   // self-loop
            float ev = asf[(size_t)n * 4 + head] + adh; ev = fmaxf(ev, 0.2f * ev);
            float p = __expf(ev);
            unsigned int v = *(const unsigned int*)(hbf + (size_t)n * 128 + 2 * lane);
            den += p;
            a0 += p * b2f((unsigned short)v);
            a1 += p * b2f((unsigned short)(v >> 16));
        }
        for (int e = 0; e < E; ++e) {
            int d = edge_at(idx32, idx64, is64, (long long)E + e);
            if (d == n) {
                int s = edge_at(idx32, idx64, is64, e);
                float ev = asf[(size_t)s * 4 + head] + adh; ev = fmaxf(ev, 0.2f * ev);
                float p = __expf(ev);
                unsigned int v = *(const unsigned int*)(hbf + (size_t)s * 128 + 2 * lane);
                den += p;
                a0 += p * b2f((unsigned short)v);
                a1 += p * b2f((unsigned short)(v >> 16));
            }
        }
        invh = 1.0f / (den + 1e-16f);
    }

    a0 = a0 * invh + b0;
    a1 = a1 * invh + b1;
    if (flags[1]) {
        unsigned int pk = (unsigned int)f2b(a0) | ((unsigned int)f2b(a1) << 16);
        ((unsigned int*)outv)[(size_t)n * 64 + lane] = pk;
    } else {
        float2 f2; f2.x = a0; f2.y = a1;
        *(float2*)((float*)outv + (size_t)n * 128 + 2 * lane) = f2;
    }
}

// ---------------------------------------------------------------------------
extern "C" void kernel_launch(void* const* d_in, const int* in_sizes, int n_in,
                              void* d_out, int out_size, void* d_ws, size_t ws_size,
                              hipStream_t stream) {
    const void*      xv    = d_in[0];
    const int*       idx32 = (const int*)d_in[1];
    const long long* idx64 = (const long long*)d_in[1];

    int N = in_sizes[0] / 128;
    int E = in_sizes[1] / 2;

    char* ws = (char*)d_ws;
    size_t o = 0;
    auto alloc = [&](size_t bytes) {
        size_t r = o; o += (bytes + 255) & ~(size_t)255; return r;
    };
    unsigned short* hbf = (unsigned short*)(ws + alloc((size_t)N * 128 * 2));
    _Float16* Wth = (_Float16*)(ws + alloc(16384 * 2));
    _Float16* Wtl = (_Float16*)(ws + alloc(16384 * 2));
    float* attf  = (float*)(ws + alloc(256 * 4));
    float* biasf = (float*)(ws + alloc(128 * 4));
    float* asf   = (float*)(ws + alloc((size_t)N * 4 * 4));
    float* adf   = (float*)(ws + alloc((size_t)N * 4 * 4));
    int* cnt     = (int*)(ws + alloc((size_t)N * CNTS * 4));
    int* flags   = (int*)(ws + alloc(256));
    int* esrc    = (int*)(ws + alloc((size_t)N * SLOT * 4));
    int NBK = (N + 63) >> 6;
    int* bcnt      = (int*)(ws + alloc((size_t)NBK * BCNS * 4));
    unsigned* bdat = (unsigned*)(ws + alloc((size_t)NBK * BCAP * 4));

    int Gg = (N + 63) / 64;                  // gemm tiles (64 rows each)
    int SB = (E + KCH - 1) / KCH;            // scatter chunks
    int NB = SB + Gg;

    k_prep<<<16, 256, 0, stream>>>(d_in[2], d_in[3], d_in[4], d_in[5],
                                   idx32, (const unsigned int*)xv, flags,
                                   Wth, Wtl, attf, biasf,
                                   bcnt, (NBK <= MAXB) ? NBK * BCNS : 0);
    if (NBK <= MAXB) {
        k_gemm_scatter<<<NB, 256, 0, stream>>>(xv, Wth, Wtl, attf, flags, hbf, asf, adf, N,
                                               idx32, idx64, bcnt, bdat, cnt, esrc, E, Gg, SB);
        k_bagg<<<NBK * 2, 256, 0, stream>>>(bdat, bcnt, hbf, asf, adf, idx32, idx64,
                                            biasf, flags, d_out, N, E);
    } else {
        hipMemsetAsync(cnt, 0, (size_t)N * CNTS * 4, stream);
        k_gemm_scatter<<<NB, 256, 0, stream>>>(xv, Wth, Wtl, attf, flags, hbf, asf, adf, N,
                                               idx32, idx64, bcnt, bdat, cnt, esrc, E, Gg, SB);
        k_aggregate<<<(N + 3) / 4, 256, 0, stream>>>(hbf, asf, adf, cnt, esrc, idx32, idx64,
                                                     biasf, flags, d_out, N, E);
    }
}